// Round 2
// baseline (5239.861 us; speedup 1.0000x reference)
//
#include <hip/hip_runtime.h>
#include <math.h>

#define SLOPE 0.2f
#define EPSV 1e-12f
#define NEGINF (-3.0e38f)
#define EPPB 4

static __device__ __forceinline__ float lrelu_combine(float xv, float dvv, float dot, float dsq) {
  float xneg = xv - dot / (dsq + EPSV) * dvv;
  float w = (dot >= 0.f) ? xv : xneg;
  return SLOPE * xv + (1.f - SLOPE) * w;
}

// ---------------- squared norms per point ----------------
__global__ void k_xx(const float* __restrict__ x, float* __restrict__ xx, int D, int N) {
  int b = blockIdx.y;
  int m = blockIdx.x * 256 + threadIdx.x;
  if (m >= N) return;
  const float* xp = x + (size_t)b * D * N + m;
  float s = 0.f;
  for (int d = 0; d < D; ++d) { float v = xp[(size_t)d * N]; s = fmaf(v, v, s); }
  xx[b * N + m] = s;
}

// ---------------- knn top-16 (matches lax.top_k order & ties) ----------------
__global__ void __launch_bounds__(256) k_knn(const float* __restrict__ x,
                                             const float* __restrict__ xx,
                                             int* __restrict__ idx, int D, int N) {
  __shared__ float dist[2048];
  __shared__ float q[192];
  __shared__ float rv[256];
  __shared__ int   ri[256];
  int b = blockIdx.y, n = blockIdx.x, tid = threadIdx.x;
  const float* xb = x + (size_t)b * D * N;
  for (int d = tid; d < D; d += 256) q[d] = xb[(size_t)d * N + n];
  __syncthreads();
  float xxn = xx[b * N + n];
  for (int m = tid; m < N; m += 256) {
    float dot = 0.f;
    for (int d = 0; d < D; ++d) dot = fmaf(q[d], xb[(size_t)d * N + m], dot);
    dist[m] = 2.f * dot - xxn - xx[b * N + m];
  }
  __syncthreads();
  for (int r = 0; r < 16; ++r) {
    float bv = NEGINF; int bi = N;
    for (int m = tid; m < N; m += 256) {
      float v = dist[m];
      if (v > bv || (v == bv && m < bi)) { bv = v; bi = m; }
    }
    rv[tid] = bv; ri[tid] = bi;
    __syncthreads();
    for (int s = 128; s > 0; s >>= 1) {
      if (tid < s) {
        float v2 = rv[tid + s]; int i2 = ri[tid + s];
        if (v2 > rv[tid] || (v2 == rv[tid] && i2 < ri[tid])) { rv[tid] = v2; ri[tid] = i2; }
      }
      __syncthreads();
    }
    if (tid == 0) { idx[((size_t)b * N + n) * 16 + r] = ri[0]; dist[ri[0]] = NEGINF; }
    __syncthreads();
  }
}

// ---------------- vn_dgcnn edge conv: mean_j lrelu(W*[nbr-ctr;ctr]) ----------------
__global__ void __launch_bounds__(192) k_edge(const float* __restrict__ x,
                                              const int* __restrict__ idx,
                                              const float* __restrict__ w,
                                              const float* __restrict__ wd,
                                              float* __restrict__ out, int C, int N) {
  __shared__ float wT[128 * 64];
  __shared__ float wdT[64 * 64];
  __shared__ float f[3][128];
  __shared__ float xl[3][64];
  __shared__ float dv[3][64];
  int tid = threadIdx.x;
  int o = tid & 63, dd = tid >> 6;
  int C2 = 2 * C;
  for (int i = tid; i < C2 * 64; i += 192) { int c = i >> 6, oo = i & 63; wT[i] = w[oo * C2 + c]; }
  for (int i = tid; i < 64 * 64; i += 192) { int p = i >> 6, oo = i & 63; wdT[i] = wd[oo * 64 + p]; }
  __syncthreads();
  int b = blockIdx.y;
  const float* xb = x + (size_t)b * C * 3 * N;
  for (int p = 0; p < EPPB; ++p) {
    int n = blockIdx.x * EPPB + p;
    float acc = 0.f;
    for (int j = 0; j < 16; ++j) {
      int m = idx[((size_t)b * N + n) * 16 + j];
      for (int i = tid; i < C * 3; i += 192) {
        int c = i / 3, d2 = i - c * 3;
        float ctr = xb[(size_t)(c * 3 + d2) * N + n];
        float nbr = xb[(size_t)(c * 3 + d2) * N + m];
        f[d2][c] = nbr - ctr;
        f[d2][C + c] = ctr;
      }
      __syncthreads();
      float s = 0.f;
      for (int c = 0; c < C2; ++c) s = fmaf(wT[c * 64 + o], f[dd][c], s);
      xl[dd][o] = s;
      __syncthreads();
      float s2 = 0.f;
      for (int pp = 0; pp < 64; ++pp) s2 = fmaf(wdT[pp * 64 + o], xl[dd][pp], s2);
      dv[dd][o] = s2;
      __syncthreads();
      float dot = xl[0][o] * dv[0][o] + xl[1][o] * dv[1][o] + xl[2][o] * dv[2][o];
      float dsq = dv[0][o] * dv[0][o] + dv[1][o] * dv[1][o] + dv[2][o] * dv[2][o];
      acc += lrelu_combine(xl[dd][o], dv[dd][o], dot, dsq);
      __syncthreads();
    }
    out[((size_t)(b * 64 + o) * 3 + dd) * N + n] = acc * (1.f / 16.f);
  }
}

// ---------------- Qx = chnorm(vn_lin_lrelu(x, qw, qd)) ----------------
__global__ void __launch_bounds__(192) k_qx(const float* __restrict__ x,
                                            const float* __restrict__ w,
                                            const float* __restrict__ wd,
                                            float* __restrict__ out, int N) {
  __shared__ float wT[64 * 64];
  __shared__ float wdT[64 * 64];
  __shared__ float f[3][64];
  __shared__ float xl[3][64];
  __shared__ float dv[3][64];
  __shared__ float nrm2[64];
  __shared__ float cn2s;
  int tid = threadIdx.x, o = tid & 63, dd = tid >> 6;
  for (int i = tid; i < 64 * 64; i += 192) {
    int c = i >> 6, oo = i & 63;
    wT[i] = w[oo * 64 + c];
    wdT[i] = wd[oo * 64 + c];
  }
  __syncthreads();
  int b = blockIdx.y;
  const float* xb = x + (size_t)b * 64 * 3 * N;
  for (int p = 0; p < EPPB; ++p) {
    int n = blockIdx.x * EPPB + p;
    f[dd][o] = xb[(size_t)(o * 3 + dd) * N + n];
    __syncthreads();
    float s = 0.f;
    for (int c = 0; c < 64; ++c) s = fmaf(wT[c * 64 + o], f[dd][c], s);
    xl[dd][o] = s;
    __syncthreads();
    float s2 = 0.f;
    for (int pp = 0; pp < 64; ++pp) s2 = fmaf(wdT[pp * 64 + o], xl[dd][pp], s2);
    dv[dd][o] = s2;
    __syncthreads();
    float dot = xl[0][o] * dv[0][o] + xl[1][o] * dv[1][o] + xl[2][o] * dv[2][o];
    float dsq = dv[0][o] * dv[0][o] + dv[1][o] * dv[1][o] + dv[2][o] * dv[2][o];
    float z = lrelu_combine(xl[dd][o], dv[dd][o], dot, dsq);
    __syncthreads();
    xl[dd][o] = z;
    __syncthreads();
    if (dd == 0) {
      float t = xl[0][o] * xl[0][o] + xl[1][o] * xl[1][o] + xl[2][o] * xl[2][o];
      nrm2[o] = t;
      float tot = t;
      for (int s3 = 32; s3 > 0; s3 >>= 1) tot += __shfl_down(tot, s3, 64);
      if (o == 0) cn2s = tot;
    }
    __syncthreads();
    float n_o = sqrtf(nrm2[o]);
    float cn = sqrtf(cn2s);
    float xdir = z / fmaxf(n_o, EPSV);
    out[((size_t)(b * 64 + o) * 3 + dd) * N + n] = xdir * (n_o / fmaxf(cn, EPSV));
    __syncthreads();
  }
}

// ---------------- Ky=chnorm(lrelu(kw*yg)) ; logits = sum_head(Ky.Qx)/sqrt(96) ----------------
__global__ void __launch_bounds__(192) k_klog(const float* __restrict__ qx,
                                              const float* __restrict__ y,
                                              const int* __restrict__ idxy,
                                              const float* __restrict__ kw,
                                              const float* __restrict__ kd,
                                              float* __restrict__ logits, int N) {
  __shared__ float wT[128 * 64];
  __shared__ float wdT[64 * 64];
  __shared__ float f[3][128];
  __shared__ float xl[3][64];
  __shared__ float dv[3][64];
  __shared__ float nrm2[64];
  __shared__ float cn2s;
  __shared__ float hsum[3][2];
  int tid = threadIdx.x, o = tid & 63, dd = tid >> 6;
  for (int i = tid; i < 128 * 64; i += 192) { int c = i >> 6, oo = i & 63; wT[i] = kw[oo * 128 + c]; }
  for (int i = tid; i < 64 * 64; i += 192)  { int c = i >> 6, oo = i & 63; wdT[i] = kd[oo * 64 + c]; }
  __syncthreads();
  int b = blockIdx.y;
  const float* yb = y + (size_t)b * 64 * 3 * N;
  const float scl = sqrtf(96.f);
  for (int p = 0; p < EPPB; ++p) {
    int n = blockIdx.x * EPPB + p;
    float qv = qx[((size_t)(b * 64 + o) * 3 + dd) * N + n];
    for (int j = 0; j < 16; ++j) {
      int m = idxy[((size_t)b * N + n) * 16 + j];
      {
        float ctr = yb[(size_t)(o * 3 + dd) * N + n];
        float nbr = yb[(size_t)(o * 3 + dd) * N + m];
        f[dd][o] = nbr - ctr;
        f[dd][64 + o] = ctr;
      }
      __syncthreads();
      float s = 0.f;
      for (int c = 0; c < 128; ++c) s = fmaf(wT[c * 64 + o], f[dd][c], s);
      xl[dd][o] = s;
      __syncthreads();
      float s2 = 0.f;
      for (int pp = 0; pp < 64; ++pp) s2 = fmaf(wdT[pp * 64 + o], xl[dd][pp], s2);
      dv[dd][o] = s2;
      __syncthreads();
      float dot = xl[0][o] * dv[0][o] + xl[1][o] * dv[1][o] + xl[2][o] * dv[2][o];
      float dsq = dv[0][o] * dv[0][o] + dv[1][o] * dv[1][o] + dv[2][o] * dv[2][o];
      float z = lrelu_combine(xl[dd][o], dv[dd][o], dot, dsq);
      __syncthreads();
      xl[dd][o] = z;
      __syncthreads();
      if (dd == 0) {
        float t = xl[0][o] * xl[0][o] + xl[1][o] * xl[1][o] + xl[2][o] * xl[2][o];
        nrm2[o] = t;
        float tot = t;
        for (int s3 = 32; s3 > 0; s3 >>= 1) tot += __shfl_down(tot, s3, 64);
        if (o == 0) cn2s = tot;
      }
      __syncthreads();
      float n_o = sqrtf(nrm2[o]);
      float cn = sqrtf(cn2s);
      float ky = (z / fmaxf(n_o, EPSV)) * (n_o / fmaxf(cn, EPSV));
      float part = ky * qv;
      for (int s3 = 16; s3 > 0; s3 >>= 1) part += __shfl_down(part, s3, 32);
      if ((o & 31) == 0) hsum[dd][o >> 5] = part;
      __syncthreads();
      if (tid < 2)
        logits[(((size_t)b * 2 + tid) * N + n) * 16 + j] =
            (hsum[0][tid] + hsum[1][tid] + hsum[2][tid]) / scl;
      __syncthreads();
    }
  }
}

// ---------------- out = x + sum_j att[h,j] * lrelu(vw*yg) ----------------
__global__ void __launch_bounds__(192) k_attout(const float* __restrict__ xres,
                                                const float* __restrict__ y,
                                                const int* __restrict__ idxy,
                                                const float* __restrict__ logits,
                                                const float* __restrict__ vw,
                                                const float* __restrict__ vd,
                                                float* __restrict__ out, int N) {
  __shared__ float wT[128 * 64];
  __shared__ float wdT[64 * 64];
  __shared__ float f[3][128];
  __shared__ float xl[3][64];
  __shared__ float dv[3][64];
  __shared__ float attS[2][16];
  int tid = threadIdx.x, o = tid & 63, dd = tid >> 6;
  for (int i = tid; i < 128 * 64; i += 192) { int c = i >> 6, oo = i & 63; wT[i] = vw[oo * 128 + c]; }
  for (int i = tid; i < 64 * 64; i += 192)  { int c = i >> 6, oo = i & 63; wdT[i] = vd[oo * 64 + c]; }
  __syncthreads();
  int b = blockIdx.y;
  const float* yb = y + (size_t)b * 64 * 3 * N;
  int h = o >> 5;
  for (int p = 0; p < EPPB; ++p) {
    int n = blockIdx.x * EPPB + p;
    if (tid < 2) {
      const float* lp = logits + (((size_t)b * 2 + tid) * N + n) * 16;
      float mx = lp[0];
      for (int j = 1; j < 16; ++j) mx = fmaxf(mx, lp[j]);
      float e[16]; float sum = 0.f;
      for (int j = 0; j < 16; ++j) { e[j] = expf(lp[j] - mx); sum += e[j]; }
      for (int j = 0; j < 16; ++j) attS[tid][j] = e[j] / sum;
    }
    __syncthreads();
    float acc = 0.f;
    for (int j = 0; j < 16; ++j) {
      int m = idxy[((size_t)b * N + n) * 16 + j];
      {
        float ctr = yb[(size_t)(o * 3 + dd) * N + n];
        float nbr = yb[(size_t)(o * 3 + dd) * N + m];
        f[dd][o] = nbr - ctr;
        f[dd][64 + o] = ctr;
      }
      __syncthreads();
      float s = 0.f;
      for (int c = 0; c < 128; ++c) s = fmaf(wT[c * 64 + o], f[dd][c], s);
      xl[dd][o] = s;
      __syncthreads();
      float s2 = 0.f;
      for (int pp = 0; pp < 64; ++pp) s2 = fmaf(wdT[pp * 64 + o], xl[dd][pp], s2);
      dv[dd][o] = s2;
      __syncthreads();
      float dot = xl[0][o] * dv[0][o] + xl[1][o] * dv[1][o] + xl[2][o] * dv[2][o];
      float dsq = dv[0][o] * dv[0][o] + dv[1][o] * dv[1][o] + dv[2][o] * dv[2][o];
      float z = lrelu_combine(xl[dd][o], dv[dd][o], dot, dsq);
      acc = fmaf(attS[h][j], z, acc);
      __syncthreads();
    }
    out[((size_t)(b * 64 + o) * 3 + dd) * N + n] =
        xres[((size_t)(b * 64 + o) * 3 + dd) * N + n] + acc;
    __syncthreads();
  }
}

// ---------------- column mean over N for all 192 (c,dd) ----------------
__global__ void k_cmean(const float* __restrict__ x, float* __restrict__ out,
                        int N, int ostride, int obase, float inv) {
  __shared__ float red[256];
  int b = blockIdx.y, cd = blockIdx.x, tid = threadIdx.x;
  const float* p = x + ((size_t)b * 192 + cd) * N;
  float s = 0.f;
  for (int i = tid; i < N; i += 256) s += p[i];
  red[tid] = s;
  __syncthreads();
  for (int st = 128; st > 0; st >>= 1) {
    if (tid < st) red[tid] += red[tid + st];
    __syncthreads();
  }
  if (tid == 0) out[(size_t)b * ostride + obase + cd] = red[0] * inv;
}

// ---------------- vn_lin_lrelu(concat[x, mean], gw, gd) ----------------
__global__ void __launch_bounds__(192) k_gfuse(const float* __restrict__ x,
                                               const float* __restrict__ meanb,
                                               const float* __restrict__ gw,
                                               const float* __restrict__ gd,
                                               float* __restrict__ out, int N) {
  __shared__ float wT[128 * 64];
  __shared__ float wdT[64 * 64];
  __shared__ float f[3][128];
  __shared__ float xl[3][64];
  __shared__ float dv[3][64];
  __shared__ float mS[192];
  int tid = threadIdx.x, o = tid & 63, dd = tid >> 6;
  for (int i = tid; i < 128 * 64; i += 192) { int c = i >> 6, oo = i & 63; wT[i] = gw[oo * 128 + c]; }
  for (int i = tid; i < 64 * 64; i += 192)  { int c = i >> 6, oo = i & 63; wdT[i] = gd[oo * 64 + c]; }
  int b = blockIdx.y;
  if (tid < 192) mS[tid] = meanb[(size_t)b * 192 + tid];
  __syncthreads();
  const float* xb = x + (size_t)b * 64 * 3 * N;
  for (int p = 0; p < EPPB; ++p) {
    int n = blockIdx.x * EPPB + p;
    f[dd][o] = xb[(size_t)(o * 3 + dd) * N + n];
    f[dd][64 + o] = mS[o * 3 + dd];
    __syncthreads();
    float s = 0.f;
    for (int c = 0; c < 128; ++c) s = fmaf(wT[c * 64 + o], f[dd][c], s);
    xl[dd][o] = s;
    __syncthreads();
    float s2 = 0.f;
    for (int pp = 0; pp < 64; ++pp) s2 = fmaf(wdT[pp * 64 + o], xl[dd][pp], s2);
    dv[dd][o] = s2;
    __syncthreads();
    float dot = xl[0][o] * dv[0][o] + xl[1][o] * dv[1][o] + xl[2][o] * dv[2][o];
    float dsq = dv[0][o] * dv[0][o] + dv[1][o] * dv[1][o] + dv[2][o] * dv[2][o];
    out[((size_t)(b * 64 + o) * 3 + dd) * N + n] =
        lrelu_combine(xl[dd][o], dv[dd][o], dot, dsq);
    __syncthreads();
  }
}

// ---------------- channel-mean (fx_par pre-normalization) for both arrays ----------------
__global__ void k_parmean(const float* __restrict__ fx, const float* __restrict__ fy,
                          float* __restrict__ px, float* __restrict__ py, int N, int B) {
  int gi = blockIdx.x * 256 + threadIdx.x;
  int total = B * 3 * N;
  if (gi >= total) return;
  int b = gi / (3 * N);
  int r = gi - b * 3 * N;
  const float* fxb = fx + (size_t)b * 192 * N + r;
  const float* fyb = fy + (size_t)b * 192 * N + r;
  float sx = 0.f, sy = 0.f;
  for (int c = 0; c < 64; ++c) { sx += fxb[(size_t)c * 3 * N]; sy += fyb[(size_t)c * 3 * N]; }
  px[gi] = sx * (1.f / 64.f);
  py[gi] = sy * (1.f / 64.f);
}

// ---------------- score logits: sum_c (fx.px)(fy.py)  (softmax+norm skipped: monotone) ----------------
__global__ void k_dotphi(const float* __restrict__ fx, const float* __restrict__ fy,
                         const float* __restrict__ px, const float* __restrict__ py,
                         float* __restrict__ dps, int N, int B) {
  int gi = blockIdx.x * 256 + threadIdx.x;
  if (gi >= B * N) return;
  int b = gi / N, n = gi - b * N;
  const float* fxb = fx + (size_t)b * 192 * N + n;
  const float* fyb = fy + (size_t)b * 192 * N + n;
  const float* pxb = px + (size_t)b * 3 * N + n;
  const float* pyb = py + (size_t)b * 3 * N + n;
  float acc = 0.f;
  for (int c = 0; c < 64; ++c) {
    float ax = 0.f, ay = 0.f;
    for (int d = 0; d < 3; ++d) {
      ax = fmaf(fxb[(size_t)(c * 3 + d) * N], pxb[(size_t)d * N], ax);
      ay = fmaf(fyb[(size_t)(c * 3 + d) * N], pyb[(size_t)d * N], ay);
    }
    acc = fmaf(ax, ay, acc);
  }
  dps[gi] = acc;
}

// ---------------- top-N/2 selection: bitonic sort (desc value, asc index) ----------------
__global__ void __launch_bounds__(1024) k_topsel(const float* __restrict__ dps,
                                                 int* __restrict__ sel, int N, int Nh) {
  __shared__ float kv[2048];
  __shared__ int ki[2048];
  int b = blockIdx.x, tid = threadIdx.x;
  for (int i = tid; i < N; i += 1024) { kv[i] = dps[b * N + i]; ki[i] = i; }
  __syncthreads();
  for (int kk = 2; kk <= N; kk <<= 1) {
    for (int jj = kk >> 1; jj > 0; jj >>= 1) {
      for (int i = tid; i < N; i += 1024) {
        int ixj = i ^ jj;
        if (ixj > i) {
          float va = kv[i], vb = kv[ixj];
          int ia = ki[i], ib = ki[ixj];
          bool aFirst = (va > vb) || (va == vb && ia < ib);
          bool up = ((i & kk) == 0);
          bool doswap = up ? (!aFirst) : aFirst;
          if (doswap) { kv[i] = vb; kv[ixj] = va; ki[i] = ib; ki[ixj] = ia; }
        }
      }
      __syncthreads();
    }
  }
  for (int i = tid; i < Nh; i += 1024) sel[b * Nh + i] = ki[i];
}

// ---------------- gather selected points for both arrays ----------------
__global__ void k_gather(const float* __restrict__ sx, const float* __restrict__ sy,
                         const int* __restrict__ sel,
                         float* __restrict__ dx, float* __restrict__ dy,
                         int N, int Nh, int B) {
  int gi = blockIdx.x * 256 + threadIdx.x;
  int total = B * 192 * Nh;
  if (gi >= total) return;
  int i = gi % Nh;
  int t = gi / Nh;
  int cd = t % 192;
  int b = t / 192;
  int s = sel[b * Nh + i];
  dx[gi] = sx[((size_t)b * 192 + cd) * N + s];
  dy[gi] = sy[((size_t)b * 192 + cd) * N + s];
}

// ---------------- final head: vn_lin_lrelu(concat blocks, h_w, h_d) ----------------
__global__ void k_head(const float* __restrict__ blkX, const float* __restrict__ blkY,
                       const float* __restrict__ hw, const float* __restrict__ hd,
                       float* __restrict__ Fx, float* __restrict__ Fy) {
  __shared__ float f[3][128];
  __shared__ float xl[3][32];
  __shared__ float dv[3][32];
  int which = blockIdx.x, b = blockIdx.y, tid = threadIdx.x;
  const float* blk = which ? blkY : blkX;
  float* F = which ? Fy : Fx;
  int o = tid & 31, dd = tid >> 5;
  for (int i = tid; i < 384; i += 96) f[i % 3][i / 3] = blk[(size_t)b * 384 + i];
  __syncthreads();
  float s = 0.f;
  for (int c = 0; c < 128; ++c) s = fmaf(hw[o * 128 + c], f[dd][c], s);
  xl[dd][o] = s;
  __syncthreads();
  float s2 = 0.f;
  for (int p = 0; p < 32; ++p) s2 = fmaf(hd[o * 32 + p], xl[dd][p], s2);
  dv[dd][o] = s2;
  __syncthreads();
  float dot = xl[0][o] * dv[0][o] + xl[1][o] * dv[1][o] + xl[2][o] * dv[2][o];
  float dsq = dv[0][o] * dv[0][o] + dv[1][o] * dv[1][o] + dv[2][o] * dv[2][o];
  F[((size_t)b * 32 + o) * 3 + dd] = lrelu_combine(xl[dd][o], dv[dd][o], dot, dsq);
}

// ================== LAPACK-faithful 3x3 SVD (dgesdd path: dgebrd + dbdsqr) ==================
// numpy's svd -> dgesdd -> dgebrd, dbdsdc(n<=smlsiz) -> dlasdq -> dbdsqr.
// Sign conventions must be reproduced exactly (R = U @ vh^T is sign-dependent).
#define DEPS 2.220446049250313e-16
#define DUNFL 2.2250738585072014e-308

// LAPACK >=3.10 dlartg convention (modern OpenBLAS/numpy): c>=0, r=sign(f)*hypot.
static __device__ void dlartg_(double f, double g, double* cs, double* sn, double* r) {
  if (g == 0.0) { *cs = 1.0; *sn = 0.0; *r = f; }
  else if (f == 0.0) { *cs = 0.0; *sn = copysign(1.0, g); *r = fabs(g); }
  else {
    double d = sqrt(f * f + g * g);
    double c = fabs(f) / d;
    double rr = copysign(d, f);
    *cs = c; *r = rr; *sn = g / rr;
  }
}

static __device__ void dlas2_(double f, double g, double h, double* ssmin, double* ssmax) {
  double fa = fabs(f), ga = fabs(g), ha = fabs(h);
  double fhmn = fmin(fa, ha), fhmx = fmax(fa, ha);
  if (fhmn == 0.0) {
    *ssmin = 0.0;
    if (fhmx == 0.0) *ssmax = ga;
    else { double mx = fmax(fhmx, ga), mn = fmin(fhmx, ga); double q = mn / mx; *ssmax = mx * sqrt(1.0 + q * q); }
  } else {
    if (ga < fhmx) {
      double as_ = 1.0 + fhmn / fhmx;
      double at = (fhmx - fhmn) / fhmx;
      double au = ga / fhmx; au = au * au;
      double c = 2.0 / (sqrt(as_ * as_ + au) + sqrt(at * at + au));
      *ssmin = fhmn * c; *ssmax = fhmx / c;
    } else {
      double au = fhmx / ga;
      if (au == 0.0) { *ssmin = (fhmn * fhmx) / ga; *ssmax = ga; }
      else {
        double as_ = 1.0 + fhmn / fhmx;
        double at = (fhmx - fhmn) / fhmx;
        double t1 = as_ * au, t2 = at * au;
        double c = 1.0 / (sqrt(1.0 + t1 * t1) + sqrt(1.0 + t2 * t2));
        double sm = (fhmn * c) * au; *ssmin = sm + sm;
        *ssmax = ga / (c + c);
      }
    }
  }
}

static __device__ void dlasv2_(double f, double g, double h,
                               double* ssmin, double* ssmax,
                               double* snr, double* csr, double* snl, double* csl) {
  double ft = f, fa = fabs(f), ht = h, ha = fabs(h);
  int pmax = 1;
  bool swp = (ha > fa);
  if (swp) { pmax = 3; double t = ft; ft = ht; ht = t; t = fa; fa = ha; ha = t; }
  double gt = g, ga = fabs(g);
  double clt = 0, crt = 0, slt = 0, srt = 0;
  if (ga == 0.0) {
    *ssmin = ha; *ssmax = fa; clt = 1.0; crt = 1.0; slt = 0.0; srt = 0.0;
  } else {
    bool gasmal = true;
    if (ga > fa) {
      pmax = 2;
      if ((fa / ga) < DEPS) {
        gasmal = false;
        *ssmax = ga;
        *ssmin = (ha > 1.0) ? (fa / (ga / ha)) : ((fa / ga) * ha);
        clt = 1.0; slt = ht / gt; srt = 1.0; crt = ft / gt;
      }
    }
    if (gasmal) {
      double dd = fa - ha;
      double l = (dd == fa) ? 1.0 : (dd / fa);
      double mq = gt / ft;
      double t = 2.0 - l;
      double mm = mq * mq, tt = t * t;
      double s = sqrt(tt + mm);
      double r = (l == 0.0) ? fabs(mq) : sqrt(l * l + mm);
      double a = 0.5 * (s + r);
      *ssmin = ha / a;
      *ssmax = fa * a;
      if (mm == 0.0) {
        if (l == 0.0) t = copysign(2.0, ft) * copysign(1.0, gt);
        else t = gt / copysign(dd, ft) + mq / t;
      } else {
        t = (mq / (s + t) + mq / (r + l)) * (1.0 + a);
      }
      double l2 = sqrt(t * t + 4.0);
      crt = 2.0 / l2;
      srt = t / l2;
      clt = (crt + srt * mq) / a;
      slt = (ht / ft) * srt / a;
    }
  }
  if (swp) { *csl = srt; *snl = crt; *csr = slt; *snr = clt; }
  else { *csl = clt; *snl = slt; *csr = crt; *snr = srt; }
  double tsign = 0.0;
  if (pmax == 1) tsign = copysign(1.0, *csr) * copysign(1.0, *csl) * copysign(1.0, f);
  if (pmax == 2) tsign = copysign(1.0, *snr) * copysign(1.0, *csl) * copysign(1.0, g);
  if (pmax == 3) tsign = copysign(1.0, *snr) * copysign(1.0, *snl) * copysign(1.0, h);
  *ssmax = copysign(*ssmax, tsign);
  *ssmin = copysign(*ssmin, tsign * copysign(1.0, f) * copysign(1.0, h));
}

// DBDSQR, n=3, upper bidiagonal, U=VT=I on entry. 1-based indices mirrored from LAPACK.
static __device__ void dbdsqr3(double d[3], double e[2], double VT[3][3], double U[3][3]) {
  const int n = 3;
  double tolmul = fmax(10.0, fmin(100.0, pow(DEPS, -0.125)));
  double tol = tolmul * DEPS;
  double thresh;
  {
    double sminoa = fabs(d[0]);
    if (sminoa != 0.0) {
      double mu = sminoa;
      for (int i = 1; i < n; ++i) {
        mu = fabs(d[i]) * (mu / (mu + fabs(e[i - 1])));
        sminoa = fmin(sminoa, mu);
        if (sminoa == 0.0) break;
      }
    }
    sminoa = sminoa / sqrt((double)n);
    thresh = fmax(tol * sminoa, 6.0 * n * n * DUNFL);
  }
  int maxit = 6 * n * n;
  int iter = 0, oldll = -1, oldm = -1, idir = 0;
  int m = n;
  double sminl = 0.0;
  int guard = 0;
  while (true) {
    if (m <= 1) break;
    if (iter > maxit) break;
    if (++guard > 500) break;
    double smaxb = fabs(d[m - 1]);
    int ll = 0; bool found = false;
    for (int lll = 1; lll <= m - 1; ++lll) {
      int l = m - lll;
      double abss = fabs(d[l - 1]);
      double abse = fabs(e[l - 1]);
      if (abse <= thresh) { ll = l; found = true; break; }
      smaxb = fmax(smaxb, fmax(abss, abse));
    }
    if (found) {
      e[ll - 1] = 0.0;
      if (ll == m - 1) { m = m - 1; continue; }
      ll = ll + 1;
    } else ll = 1;
    if (ll == m - 1) {
      // 2x2 block
      double sigmn, sigmx, sinr, cosr, sinl2, cosl2;
      dlasv2_(d[m - 2], e[m - 2], d[m - 1], &sigmn, &sigmx, &sinr, &cosr, &sinl2, &cosl2);
      d[m - 2] = sigmx; d[m - 1] = sigmn; e[m - 2] = 0.0;
      for (int j = 0; j < 3; ++j) {
        double t1 = VT[m - 2][j], t2 = VT[m - 1][j];
        VT[m - 2][j] = cosr * t1 + sinr * t2;
        VT[m - 1][j] = cosr * t2 - sinr * t1;
      }
      for (int i2 = 0; i2 < 3; ++i2) {
        double t1 = U[i2][m - 2], t2 = U[i2][m - 1];
        U[i2][m - 2] = cosl2 * t1 + sinl2 * t2;
        U[i2][m - 1] = cosl2 * t2 - sinl2 * t1;
      }
      m -= 2;
      continue;
    }
    if (ll > oldm || m < oldll)
      idir = (fabs(d[ll - 1]) >= fabs(d[m - 1])) ? 1 : 2;
    if (idir == 1) {
      if (fabs(e[m - 2]) <= tol * fabs(d[m - 1])) { e[m - 2] = 0.0; continue; }
      double mu = fabs(d[ll - 1]); sminl = mu;
      bool conv = true;
      for (int lll = ll; lll <= m - 1; ++lll) {
        if (fabs(e[lll - 1]) > tol * mu) { conv = false; break; }
        mu = fabs(d[lll]) * (mu / (mu + fabs(e[lll - 1])));
        sminl = fmin(sminl, mu);
      }
      if (conv) { e[m - 2] = 0.0; continue; }
    } else {
      if (fabs(e[ll - 1]) <= tol * fabs(d[ll - 1])) { e[ll - 1] = 0.0; continue; }
      double mu = fabs(d[m - 1]); sminl = mu;
      bool conv = true;
      for (int lll = m - 1; lll >= ll; --lll) {
        if (fabs(e[lll - 1]) > tol * mu) { conv = false; break; }
        mu = fabs(d[lll - 1]) * (mu / (mu + fabs(e[lll - 1])));
        sminl = fmin(sminl, mu);
      }
      if (conv) { e[ll - 1] = 0.0; continue; }
    }
    oldll = ll; oldm = m;
    double shift = 0.0, rr;
    if (!(n * tol * (sminl / smaxb) <= fmax(DEPS, 0.01 * tol))) {
      double sll;
      if (idir == 1) { sll = fabs(d[ll - 1]); dlas2_(d[m - 2], e[m - 2], d[m - 1], &shift, &rr); }
      else { sll = fabs(d[m - 1]); dlas2_(d[ll - 1], e[ll - 1], d[ll], &shift, &rr); }
      if (sll > 0.0) { double q = shift / sll; if (q * q < DEPS) shift = 0.0; }
    }
    iter += m - ll;
    double csv[2], snv[2], ocsv[2], osnv[2];
    int cnt = 0;
    if (shift == 0.0) {
      if (idir == 1) {
        double cs = 1.0, oldcs = 1.0, sn = 0.0, oldsn = 0.0, r;
        for (int i = ll; i <= m - 1; ++i) {
          dlartg_(d[i - 1] * cs, e[i - 1], &cs, &sn, &r);
          if (i > ll) e[i - 2] = oldsn * r;
          dlartg_(oldcs * r, d[i] * sn, &oldcs, &oldsn, &d[i - 1]);
          csv[cnt] = cs; snv[cnt] = sn; ocsv[cnt] = oldcs; osnv[cnt] = oldsn; cnt++;
        }
        double hh = d[m - 1] * cs;
        d[m - 1] = hh * oldcs;
        e[m - 2] = hh * oldsn;
        for (int k = 0; k < cnt; ++k) {
          int r0 = ll - 1 + k, r1 = r0 + 1;
          for (int j = 0; j < 3; ++j) {
            double t1 = VT[r0][j], t2 = VT[r1][j];
            VT[r0][j] = snv[k] * t2 + csv[k] * t1;
            VT[r1][j] = csv[k] * t2 - snv[k] * t1;
          }
        }
        for (int k = 0; k < cnt; ++k) {
          int c0 = ll - 1 + k, c1 = c0 + 1;
          for (int i2 = 0; i2 < 3; ++i2) {
            double t1 = U[i2][c0], t2 = U[i2][c1];
            U[i2][c0] = osnv[k] * t2 + ocsv[k] * t1;
            U[i2][c1] = ocsv[k] * t2 - osnv[k] * t1;
          }
        }
        if (fabs(e[m - 2]) <= thresh) e[m - 2] = 0.0;
      } else {
        double cs = 1.0, oldcs = 1.0, sn = 0.0, oldsn = 0.0, r;
        for (int i = m; i >= ll + 1; --i) {
          dlartg_(d[i - 1] * cs, e[i - 2], &cs, &sn, &r);
          if (i < m) e[i - 1] = oldsn * r;
          dlartg_(oldcs * r, d[i - 2] * sn, &oldcs, &oldsn, &d[i - 1]);
          int k = i - ll - 1;
          csv[k] = cs; snv[k] = -sn; ocsv[k] = oldcs; osnv[k] = -oldsn; cnt++;
        }
        double hh = d[ll - 1] * cs;
        d[ll - 1] = hh * oldcs;
        e[ll - 1] = hh * oldsn;
        for (int k = cnt - 1; k >= 0; --k) {  // VT: (oldcs,-oldsn) backward
          int r0 = ll - 1 + k, r1 = r0 + 1;
          for (int j = 0; j < 3; ++j) {
            double t1 = VT[r0][j], t2 = VT[r1][j];
            VT[r0][j] = osnv[k] * t2 + ocsv[k] * t1;
            VT[r1][j] = ocsv[k] * t2 - osnv[k] * t1;
          }
        }
        for (int k = cnt - 1; k >= 0; --k) {  // U: (cs,-sn) backward
          int c0 = ll - 1 + k, c1 = c0 + 1;
          for (int i2 = 0; i2 < 3; ++i2) {
            double t1 = U[i2][c0], t2 = U[i2][c1];
            U[i2][c0] = snv[k] * t2 + csv[k] * t1;
            U[i2][c1] = csv[k] * t2 - snv[k] * t1;
          }
        }
        if (fabs(e[ll - 1]) <= thresh) e[ll - 1] = 0.0;
      }
    } else {
      if (idir == 1) {
        double f = (fabs(d[ll - 1]) - shift) * (copysign(1.0, d[ll - 1]) + shift / d[ll - 1]);
        double g = e[ll - 1];
        double cosr, sinr, cosl2, sinl2, r;
        for (int i = ll; i <= m - 1; ++i) {
          dlartg_(f, g, &cosr, &sinr, &r);
          if (i > ll) e[i - 2] = r;
          f = cosr * d[i - 1] + sinr * e[i - 1];
          e[i - 1] = cosr * e[i - 1] - sinr * d[i - 1];
          g = sinr * d[i];
          d[i] = cosr * d[i];
          dlartg_(f, g, &cosl2, &sinl2, &r);
          d[i - 1] = r;
          f = cosl2 * e[i - 1] + sinl2 * d[i];
          d[i] = cosl2 * d[i] - sinl2 * e[i - 1];
          if (i < m - 1) {
            g = sinl2 * e[i];
            e[i] = cosl2 * e[i];
          }
          csv[cnt] = cosr; snv[cnt] = sinr; ocsv[cnt] = cosl2; osnv[cnt] = sinl2; cnt++;
        }
        e[m - 2] = f;
        for (int k = 0; k < cnt; ++k) {  // VT: (cosr,sinr) forward
          int r0 = ll - 1 + k, r1 = r0 + 1;
          for (int j = 0; j < 3; ++j) {
            double t1 = VT[r0][j], t2 = VT[r1][j];
            VT[r0][j] = snv[k] * t2 + csv[k] * t1;
            VT[r1][j] = csv[k] * t2 - snv[k] * t1;
          }
        }
        for (int k = 0; k < cnt; ++k) {  // U: (cosl,sinl) forward
          int c0 = ll - 1 + k, c1 = c0 + 1;
          for (int i2 = 0; i2 < 3; ++i2) {
            double t1 = U[i2][c0], t2 = U[i2][c1];
            U[i2][c0] = osnv[k] * t2 + ocsv[k] * t1;
            U[i2][c1] = ocsv[k] * t2 - osnv[k] * t1;
          }
        }
        if (fabs(e[m - 2]) <= thresh) e[m - 2] = 0.0;
      } else {
        double f = (fabs(d[m - 1]) - shift) * (copysign(1.0, d[m - 1]) + shift / d[m - 1]);
        double g = e[m - 2];
        for (int i = m; i >= ll + 1; --i) {
          double cosr, sinr, cosl2, sinl2, r;
          dlartg_(f, g, &cosr, &sinr, &r);
          if (i < m) e[i - 1] = r;
          f = cosr * d[i - 1] + sinr * e[i - 2];
          e[i - 2] = cosr * e[i - 2] - sinr * d[i - 1];
          g = sinr * d[i - 2];
          d[i - 2] = cosr * d[i - 2];
          dlartg_(f, g, &cosl2, &sinl2, &r);
          d[i - 1] = r;
          f = cosl2 * e[i - 2] + sinl2 * d[i - 2];
          d[i - 2] = cosl2 * d[i - 2] - sinl2 * e[i - 2];
          if (i > ll + 1) {
            g = sinl2 * e[i - 3];
            e[i - 3] = cosl2 * e[i - 3];
          }
          int k = i - ll - 1;
          ocsv[k] = cosl2; osnv[k] = -sinl2; csv[k] = cosr; snv[k] = -sinr; cnt++;
        }
        e[ll - 1] = f;
        for (int k = cnt - 1; k >= 0; --k) {  // VT: (cosr,-sinr) backward
          int r0 = ll - 1 + k, r1 = r0 + 1;
          for (int j = 0; j < 3; ++j) {
            double t1 = VT[r0][j], t2 = VT[r1][j];
            VT[r0][j] = snv[k] * t2 + csv[k] * t1;
            VT[r1][j] = csv[k] * t2 - snv[k] * t1;
          }
        }
        for (int k = cnt - 1; k >= 0; --k) {  // U: (cosl,-sinl) backward
          int c0 = ll - 1 + k, c1 = c0 + 1;
          for (int i2 = 0; i2 < 3; ++i2) {
            double t1 = U[i2][c0], t2 = U[i2][c1];
            U[i2][c0] = osnv[k] * t2 + ocsv[k] * t1;
            U[i2][c1] = ocsv[k] * t2 - osnv[k] * t1;
          }
        }
        if (fabs(e[ll - 1]) <= thresh) e[ll - 1] = 0.0;
      }
    }
  }
  // make singular values positive: scale VT rows only (LAPACK)
  for (int i = 0; i < n; ++i)
    if (d[i] < 0.0) { d[i] = -d[i]; for (int j = 0; j < 3; ++j) VT[i][j] = -VT[i][j]; }
  // sort decreasing, LAPACK selection sort
  for (int i = 1; i <= n - 1; ++i) {
    int isub = 1; double smn = d[0];
    for (int j = 2; j <= n + 1 - i; ++j)
      if (d[j - 1] <= smn) { isub = j; smn = d[j - 1]; }
    if (isub != n + 1 - i) {
      int a = isub - 1, b2 = n - i;
      double t = d[a]; d[a] = d[b2]; d[b2] = t;
      for (int j = 0; j < 3; ++j) { t = VT[a][j]; VT[a][j] = VT[b2][j]; VT[b2][j] = t; }
      for (int j = 0; j < 3; ++j) { t = U[j][a]; U[j][a] = U[j][b2]; U[j][b2] = t; }
    }
  }
}

__global__ void k_svd(const float* __restrict__ Fx, const float* __restrict__ Fy,
                      float* __restrict__ out, int B) {
  int b = blockIdx.x;
  if (threadIdx.x != 0) return;
  double A[3][3];
  for (int d = 0; d < 3; ++d)
    for (int e = 0; e < 3; ++e) {
      double s = 0.0;
      for (int c = 0; c < 32; ++c)
        s += (double)Fx[((size_t)b * 32 + c) * 3 + d] * (double)Fy[((size_t)b * 32 + c) * 3 + e];
      A[d][e] = s;
    }
  // ---- DGEBD2 (3x3): Q = H0 H1, P = G0. beta = -sign(alpha)*hypot (dlarfg) ----
  double dg[3], eg[2], tauq0, tauq1, taup0;
  double v1_1 = 0, v1_2 = 0, v2_1 = 0, w1 = 0;
  {
    double alpha = A[0][0];
    double xn = sqrt(A[1][0] * A[1][0] + A[2][0] * A[2][0]);
    if (xn == 0.0) { tauq0 = 0.0; dg[0] = alpha; }
    else {
      double beta = -copysign(sqrt(alpha * alpha + xn * xn), alpha);
      tauq0 = (beta - alpha) / beta;
      double scal = 1.0 / (alpha - beta);
      v1_1 = A[1][0] * scal; v1_2 = A[2][0] * scal;
      dg[0] = beta;
    }
    for (int j = 1; j < 3; ++j) {
      double w = A[0][j] + v1_1 * A[1][j] + v1_2 * A[2][j];
      w *= tauq0;
      A[0][j] -= w; A[1][j] -= w * v1_1; A[2][j] -= w * v1_2;
    }
  }
  {
    double alpha = A[0][1];
    double xn = fabs(A[0][2]);
    if (xn == 0.0) { taup0 = 0.0; eg[0] = alpha; }
    else {
      double beta = -copysign(sqrt(alpha * alpha + xn * xn), alpha);
      taup0 = (beta - alpha) / beta;
      w1 = A[0][2] / (alpha - beta);
      eg[0] = beta;
    }
    for (int i = 1; i < 3; ++i) {
      double t = A[i][1] + w1 * A[i][2];
      t *= taup0;
      A[i][1] -= t; A[i][2] -= t * w1;
    }
  }
  {
    double alpha = A[1][1];
    double xn = fabs(A[2][1]);
    if (xn == 0.0) { tauq1 = 0.0; dg[1] = alpha; }
    else {
      double beta = -copysign(sqrt(alpha * alpha + xn * xn), alpha);
      tauq1 = (beta - alpha) / beta;
      v2_1 = A[2][1] / (alpha - beta);
      dg[1] = beta;
    }
    double w = A[1][2] + v2_1 * A[2][2];
    w *= tauq1;
    A[1][2] -= w; A[2][2] -= w * v2_1;
  }
  eg[1] = A[1][2];
  dg[2] = A[2][2];
  double U[3][3] = {{1, 0, 0}, {0, 1, 0}, {0, 0, 1}};
  double VT[3][3] = {{1, 0, 0}, {0, 1, 0}, {0, 0, 1}};
  dbdsqr3(dg, eg, VT, U);
  // backtransform: U = H0*(H1*U_bd)
  for (int j = 0; j < 3; ++j) {  // H1: v=(0,1,v2_1)
    double w = U[1][j] + v2_1 * U[2][j];
    w *= tauq1;
    U[1][j] -= w; U[2][j] -= w * v2_1;
  }
  for (int j = 0; j < 3; ++j) {  // H0: v=(1,v1_1,v1_2)
    double w = U[0][j] + v1_1 * U[1][j] + v1_2 * U[2][j];
    w *= tauq0;
    U[0][j] -= w; U[1][j] -= w * v1_1; U[2][j] -= w * v1_2;
  }
  // VT = VT_bd * G0, G0 = I - taup0 * w wT, w=(0,1,w1)
  for (int r = 0; r < 3; ++r) {
    double t = VT[r][1] + w1 * VT[r][2];
    t *= taup0;
    VT[r][1] -= t; VT[r][2] -= t * w1;
  }
  // R = U @ vh^T : R[i][j] = sum_k U[i][k]*VT[j][k]
  for (int i = 0; i < 3; ++i)
    for (int j = 0; j < 3; ++j) {
      double r = 0;
      for (int k = 0; k < 3; ++k) r += U[i][k] * VT[j][k];
      out[b * 9 + i * 3 + j] = (float)r;
    }
  for (int dd = 0; dd < 3; ++dd) {
    float sx = 0.f, sy = 0.f;
    for (int c = 0; c < 32; ++c) {
      float vx = Fx[((size_t)b * 32 + c) * 3 + dd];
      float vy = Fy[((size_t)b * 32 + c) * 3 + dd];
      sx = fmaf(vx, vx, sx);
      sy = fmaf(vy, vy, sy);
    }
    out[B * 9 + b * 3 + dd] = sqrtf(sy) / sqrtf(sx);
  }
}

extern "C" void kernel_launch(void* const* d_in, const int* in_sizes, int n_in,
                              void* d_out, int out_size, void* d_ws, size_t ws_size,
                              hipStream_t stream) {
  (void)in_sizes; (void)n_in; (void)out_size; (void)ws_size;
  const int B = 2, N0 = 2048;
  const float* W[24];
  for (int i = 0; i < 24; ++i) W[i] = (const float*)d_in[i];

  float* ws = (float*)d_ws;
  const size_t P = (size_t)B * 64 * 3 * 2048;  // 786432
  float* bufA = ws;
  float* bufB = bufA + P;
  float* bufC = bufB + P;
  float* bufD = bufC + P;
  float* bufQ = bufD + P;
  float* logits = bufQ + P;          // B*2*2048*16 = 131072
  float* px = logits + 131072;       // B*3*2048 = 12288
  float* py = px + 12288;
  float* dps = py + 12288;           // B*2048 = 4096
  float* xxb = dps + 4096;           // B*2048 = 4096
  float* meanX = xxb + 4096;         // 384
  float* meanY = meanX + 384;
  float* blkX = meanY + 384;         // B*128*3 = 768
  float* blkY = blkX + 768;
  float* Fxb = blkY + 768;           // B*32*3 = 192
  float* Fyb = Fxb + 192;
  int* idxA = (int*)(Fyb + 192);     // B*2048*16 = 65536
  int* idxB = idxA + 65536;
  int* sel = idxB + 65536;           // B*1024

  auto xxknn = [&](const float* x, int D, int N, int* idx) {
    dim3 g1((N + 255) / 256, B);
    k_xx<<<g1, 256, 0, stream>>>(x, xxb, D, N);
    dim3 g2(N, B);
    k_knn<<<g2, 256, 0, stream>>>(x, xxb, idx, D, N);
  };

  const float* fx = W[0];
  const float* fy = W[1];
  int N = N0;
  for (int blk = 0; blk < 2; ++blk) {
    int C = (blk == 0) ? 1 : 64;
    int D = C * 3;
    const float* dgw = W[blk ? 12 : 2]; const float* dgd = W[blk ? 13 : 3];
    const float* qw  = W[blk ? 14 : 4]; const float* qd  = W[blk ? 15 : 5];
    const float* kw  = W[blk ? 16 : 6]; const float* kd  = W[blk ? 17 : 7];
    const float* vw  = W[blk ? 18 : 8]; const float* vd  = W[blk ? 19 : 9];
    const float* gw  = W[blk ? 20 : 10]; const float* gd = W[blk ? 21 : 11];
    dim3 gp(N / EPPB, B);
    dim3 gm(192, B);
    // dgcnn on fx, fy
    xxknn(fx, D, N, idxA);
    k_edge<<<gp, 192, 0, stream>>>(fx, idxA, dgw, dgd, bufA, C, N);
    xxknn(fy, D, N, idxB);
    k_edge<<<gp, 192, 0, stream>>>(fy, idxB, dgw, dgd, bufB, C, N);
    // cross_context #1: x=bufA, y=bufB -> bufC
    xxknn(bufB, 192, N, idxB);
    k_qx<<<gp, 192, 0, stream>>>(bufA, qw, qd, bufQ, N);
    k_klog<<<gp, 192, 0, stream>>>(bufQ, bufB, idxB, kw, kd, logits, N);
    k_attout<<<gp, 192, 0, stream>>>(bufA, bufB, idxB, logits, vw, vd, bufC, N);
    // cross_context #2: x=bufB, y=bufC(updated fx) -> bufD
    xxknn(bufC, 192, N, idxA);
    k_qx<<<gp, 192, 0, stream>>>(bufB, qw, qd, bufQ, N);
    k_klog<<<gp, 192, 0, stream>>>(bufQ, bufC, idxA, kw, kd, logits, N);
    k_attout<<<gp, 192, 0, stream>>>(bufB, bufC, idxA, logits, vw, vd, bufD, N);
    // global fuse
    k_cmean<<<gm, 256, 0, stream>>>(bufC, meanX, N, 192, 0, 1.f / (float)N);
    k_cmean<<<gm, 256, 0, stream>>>(bufD, meanY, N, 192, 0, 1.f / (float)N);
    k_gfuse<<<gp, 192, 0, stream>>>(bufC, meanX, gw, gd, bufA, N);
    k_gfuse<<<gp, 192, 0, stream>>>(bufD, meanY, gw, gd, bufB, N);
    // score + top-half selection
    int Nh = N / 2;
    k_parmean<<<dim3((B * 3 * N + 255) / 256), 256, 0, stream>>>(bufA, bufB, px, py, N, B);
    k_dotphi<<<dim3((B * N + 255) / 256), 256, 0, stream>>>(bufA, bufB, px, py, dps, N, B);
    k_topsel<<<dim3(B), 1024, 0, stream>>>(dps, sel, N, Nh);
    float* gx = bufC;
    float* gy = (blk == 0) ? bufD : bufQ;
    k_gather<<<dim3((B * 192 * Nh + 255) / 256), 256, 0, stream>>>(bufA, bufB, sel, gx, gy, N, Nh, B);
    k_cmean<<<gm, 256, 0, stream>>>(gx, blkX, Nh, 384, blk * 192, 1.f / (float)Nh);
    k_cmean<<<gm, 256, 0, stream>>>(gy, blkY, Nh, 384, blk * 192, 1.f / (float)Nh);
    fx = gx; fy = gy;
    N = Nh;
  }
  k_head<<<dim3(2, B), 96, 0, stream>>>(blkX, blkY, W[22], W[23], Fxb, Fyb);
  k_svd<<<dim3(B), 64, 0, stream>>>(Fxb, Fyb, (float*)d_out, B);
}

// Round 3
// 3312.632 us; speedup vs baseline: 1.5818x; 1.5818x over previous
//
#include <hip/hip_runtime.h>
#include <math.h>

#define SLOPE 0.2f
#define EPSV 1e-12f
#define NEGINF (-3.0e38f)

static __device__ __forceinline__ float lrelu_combine(float xv, float dvv, float dot, float dsq) {
  float xneg = xv - dot / (dsq + EPSV) * dvv;
  float w = (dot >= 0.f) ? xv : xneg;
  return SLOPE * xv + (1.f - SLOPE) * w;
}

// ---------------- squared norms per point ----------------
__global__ void k_xx(const float* __restrict__ x, float* __restrict__ xx, int D, int N) {
  int b = blockIdx.y;
  int m = blockIdx.x * 256 + threadIdx.x;
  if (m >= N) return;
  const float* xp = x + (size_t)b * D * N + m;
  float s = 0.f;
  for (int d = 0; d < D; ++d) { float v = xp[(size_t)d * N]; s = fmaf(v, v, s); }
  xx[b * N + m] = s;
}

// ---------------- knn top-16 (matches lax.top_k order & ties) ----------------
__global__ void __launch_bounds__(256) k_knn(const float* __restrict__ x,
                                             const float* __restrict__ xx,
                                             int* __restrict__ idx, int D, int N) {
  __shared__ float dist[2048];
  __shared__ float q[192];
  __shared__ float rv[256];
  __shared__ int   ri[256];
  int b = blockIdx.y, n = blockIdx.x, tid = threadIdx.x;
  const float* xb = x + (size_t)b * D * N;
  for (int d = tid; d < D; d += 256) q[d] = xb[(size_t)d * N + n];
  __syncthreads();
  float xxn = xx[b * N + n];
  for (int m = tid; m < N; m += 256) {
    float dot = 0.f;
    for (int d = 0; d < D; ++d) dot = fmaf(q[d], xb[(size_t)d * N + m], dot);
    dist[m] = 2.f * dot - xxn - xx[b * N + m];
  }
  __syncthreads();
  for (int r = 0; r < 16; ++r) {
    float bv = NEGINF; int bi = N;
    for (int m = tid; m < N; m += 256) {
      float v = dist[m];
      if (v > bv || (v == bv && m < bi)) { bv = v; bi = m; }
    }
    rv[tid] = bv; ri[tid] = bi;
    __syncthreads();
    for (int s = 128; s > 0; s >>= 1) {
      if (tid < s) {
        float v2 = rv[tid + s]; int i2 = ri[tid + s];
        if (v2 > rv[tid] || (v2 == rv[tid] && i2 < ri[tid])) { rv[tid] = v2; ri[tid] = i2; }
      }
      __syncthreads();
    }
    if (tid == 0) { idx[((size_t)b * N + n) * 16 + r] = ri[0]; dist[ri[0]] = NEGINF; }
    __syncthreads();
  }
}

// ---------------- generic 64-out linear: out[b][o][d][n] = sum_k Wl[o][k]*X[b][k][d][n] + bias ----
// Wl[o][k] = W[o*ws + woff + k] - (sub ? W[o*ws + k] : 0)
template <int KT>
__global__ void __launch_bounds__(256) k_lin(const float* __restrict__ W, int ws, int woff, int sub,
                                             const float* __restrict__ X,
                                             const float* __restrict__ bias,
                                             float* __restrict__ out, int N) {
  __shared__ float wl[64 * ((KT + 3) & ~3)];
  const int KP = (KT + 3) & ~3;
  int tid = threadIdx.x;
  for (int i = tid; i < 64 * KT; i += 256) {
    int o = i / KT, k = i - o * KT;
    float v = W[o * ws + woff + k];
    if (sub) v -= W[o * ws + k];
    wl[o * KP + k] = v;
  }
  __syncthreads();
  int b = blockIdx.y;
  int oc = blockIdx.z * 16;
  int j = blockIdx.x * 256 + tid;  // column in [0, 3N)
  int M3 = 3 * N;
  if (j >= M3) return;
  const float* Xb = X + (size_t)b * KT * M3;
  float xv[KT];
#pragma unroll
  for (int k = 0; k < KT; ++k) xv[k] = Xb[(size_t)k * M3 + j];
  int d = j / N;
  float acc[16];
  if (bias) {
#pragma unroll
    for (int oo = 0; oo < 16; ++oo) acc[oo] = bias[b * 192 + (oc + oo) * 3 + d];
  } else {
#pragma unroll
    for (int oo = 0; oo < 16; ++oo) acc[oo] = 0.f;
  }
#pragma unroll
  for (int oo = 0; oo < 16; ++oo) {
    const float* wr = &wl[(oc + oo) * KP];
    float s = acc[oo];
#pragma unroll
    for (int k = 0; k < KT; ++k) s = fmaf(wr[k], xv[k], s);
    acc[oo] = s;
  }
  float* ob = out + (size_t)b * 64 * M3;
#pragma unroll
  for (int oo = 0; oo < 16; ++oo) ob[(size_t)(oc + oo) * M3 + j] = acc[oo];
}

// ---------------- edge conv via precomputed P1,P2,D1,D2: out = mean_j lrelu ----------------
__global__ void __launch_bounds__(256) k_edge2(const float* __restrict__ P1, const float* __restrict__ P2,
                                               const float* __restrict__ D1, const float* __restrict__ D2,
                                               const int* __restrict__ idx,
                                               float* __restrict__ out, int N) {
  int gi = blockIdx.x * 256 + threadIdx.x;
  int total = 2 * 64 * N;
  if (gi >= total) return;
  int n = gi % N;
  int t = gi / N;
  int o = t & 63, b = t >> 6;
  size_t r0 = (size_t)((b * 64 + o) * 3) * N;
  float p2[3], d2[3];
#pragma unroll
  for (int d = 0; d < 3; ++d) { p2[d] = P2[r0 + (size_t)d * N + n]; d2[d] = D2[r0 + (size_t)d * N + n]; }
  const int* ip = idx + ((size_t)b * N + n) * 16;
  float acc0 = 0.f, acc1 = 0.f, acc2 = 0.f;
  for (int j = 0; j < 16; ++j) {
    int m = ip[j];
    float xl[3], dv[3];
#pragma unroll
    for (int d = 0; d < 3; ++d) {
      xl[d] = P1[r0 + (size_t)d * N + m] + p2[d];
      dv[d] = D1[r0 + (size_t)d * N + m] + d2[d];
    }
    float dot = xl[0] * dv[0] + xl[1] * dv[1] + xl[2] * dv[2];
    float dsq = dv[0] * dv[0] + dv[1] * dv[1] + dv[2] * dv[2];
    acc0 += lrelu_combine(xl[0], dv[0], dot, dsq);
    acc1 += lrelu_combine(xl[1], dv[1], dot, dsq);
    acc2 += lrelu_combine(xl[2], dv[2], dot, dsq);
  }
  out[r0 + n] = acc0 * (1.f / 16.f);
  out[r0 + N + n] = acc1 * (1.f / 16.f);
  out[r0 + 2 * (size_t)N + n] = acc2 * (1.f / 16.f);
}

// ---------------- Qx finisher: lrelu + chnorm (wave per point, lane = channel) ----------------
__global__ void __launch_bounds__(256) k_qfin(const float* __restrict__ XL, const float* __restrict__ DV,
                                              float* __restrict__ out, int N) {
  int tid = threadIdx.x;
  int p = blockIdx.x * 4 + (tid >> 6);
  int c = tid & 63;
  int b = p / N, n = p - b * N;
  size_t r0 = (size_t)((b * 64 + c) * 3) * N;
  float xl[3], dv[3];
#pragma unroll
  for (int d = 0; d < 3; ++d) { xl[d] = XL[r0 + (size_t)d * N + n]; dv[d] = DV[r0 + (size_t)d * N + n]; }
  float dot = xl[0] * dv[0] + xl[1] * dv[1] + xl[2] * dv[2];
  float dsq = dv[0] * dv[0] + dv[1] * dv[1] + dv[2] * dv[2];
  float z[3];
#pragma unroll
  for (int d = 0; d < 3; ++d) z[d] = lrelu_combine(xl[d], dv[d], dot, dsq);
  float n2 = z[0] * z[0] + z[1] * z[1] + z[2] * z[2];
  float cn2 = n2;
#pragma unroll
  for (int s = 1; s < 64; s <<= 1) cn2 += __shfl_xor(cn2, s, 64);
  float n_o = sqrtf(n2), cn = sqrtf(cn2);
  float scl = (n_o / fmaxf(cn, EPSV)) / fmaxf(n_o, EPSV);
#pragma unroll
  for (int d = 0; d < 3; ++d) out[r0 + (size_t)d * N + n] = z[d] * scl;
}

// ---------------- K path: wave per edge -> logits (lane = channel) ----------------
__global__ void __launch_bounds__(256) k_klog2(const float* __restrict__ qx,
                                               const float* __restrict__ P1, const float* __restrict__ P2,
                                               const float* __restrict__ D1, const float* __restrict__ D2,
                                               const int* __restrict__ idx,
                                               float* __restrict__ logits, int N) {
  int tid = threadIdx.x;
  int e = blockIdx.x * 4 + (tid >> 6);
  int c = tid & 63;
  int b = e / (N * 16);
  int r = e - b * N * 16;
  int n = r >> 4, j = r & 15;
  int m = idx[((size_t)b * N + n) * 16 + j];
  size_t r0 = (size_t)((b * 64 + c) * 3) * N;
  float xl[3], dv[3], qv[3];
#pragma unroll
  for (int d = 0; d < 3; ++d) {
    size_t rd = r0 + (size_t)d * N;
    xl[d] = P1[rd + m] + P2[rd + n];
    dv[d] = D1[rd + m] + D2[rd + n];
    qv[d] = qx[rd + n];
  }
  float dot = xl[0] * dv[0] + xl[1] * dv[1] + xl[2] * dv[2];
  float dsq = dv[0] * dv[0] + dv[1] * dv[1] + dv[2] * dv[2];
  float z[3];
#pragma unroll
  for (int d = 0; d < 3; ++d) z[d] = lrelu_combine(xl[d], dv[d], dot, dsq);
  float n2 = z[0] * z[0] + z[1] * z[1] + z[2] * z[2];
  float cn2 = n2;
#pragma unroll
  for (int s = 1; s < 64; s <<= 1) cn2 += __shfl_xor(cn2, s, 64);
  float n_o = sqrtf(n2), cn = sqrtf(cn2);
  float scl = (n_o / fmaxf(cn, EPSV)) / fmaxf(n_o, EPSV);
  float part = (z[0] * qv[0] + z[1] * qv[1] + z[2] * qv[2]) * scl;
#pragma unroll
  for (int s = 1; s < 32; s <<= 1) part += __shfl_xor(part, s, 32);
  if ((c & 31) == 0) {
    int h = c >> 5;
    logits[(((size_t)b * 2 + h) * N + n) * 16 + j] = part * 0.102062072615966f; // 1/sqrt(96)
  }
}

// ---------------- softmax over 16 neighbors ----------------
__global__ void k_soft(const float* __restrict__ logits, float* __restrict__ att, int N) {
  int gi = blockIdx.x * 256 + threadIdx.x;
  if (gi >= 2 * 2 * N) return;
  const float* lp = logits + (size_t)gi * 16;
  float* ap = att + (size_t)gi * 16;
  float mx = lp[0];
  for (int j = 1; j < 16; ++j) mx = fmaxf(mx, lp[j]);
  float e[16]; float sum = 0.f;
  for (int j = 0; j < 16; ++j) { e[j] = expf(lp[j] - mx); sum += e[j]; }
  float inv = 1.f / sum;
  for (int j = 0; j < 16; ++j) ap[j] = e[j] * inv;
}

// ---------------- V path + attention-weighted sum + residual ----------------
__global__ void __launch_bounds__(256) k_attout2(const float* __restrict__ xres,
                                                 const float* __restrict__ P1, const float* __restrict__ P2,
                                                 const float* __restrict__ D1, const float* __restrict__ D2,
                                                 const float* __restrict__ att,
                                                 const int* __restrict__ idx,
                                                 float* __restrict__ out, int N) {
  int gi = blockIdx.x * 256 + threadIdx.x;
  int total = 2 * 64 * N;
  if (gi >= total) return;
  int n = gi % N;
  int t = gi / N;
  int o = t & 63, b = t >> 6;
  int h = o >> 5;
  size_t r0 = (size_t)((b * 64 + o) * 3) * N;
  float p2[3], d2[3];
#pragma unroll
  for (int d = 0; d < 3; ++d) { p2[d] = P2[r0 + (size_t)d * N + n]; d2[d] = D2[r0 + (size_t)d * N + n]; }
  const int* ip = idx + ((size_t)b * N + n) * 16;
  const float* ap = att + (((size_t)b * 2 + h) * N + n) * 16;
  float acc0 = 0.f, acc1 = 0.f, acc2 = 0.f;
  for (int j = 0; j < 16; ++j) {
    int m = ip[j];
    float av = ap[j];
    float xl[3], dv[3];
#pragma unroll
    for (int d = 0; d < 3; ++d) {
      xl[d] = P1[r0 + (size_t)d * N + m] + p2[d];
      dv[d] = D1[r0 + (size_t)d * N + m] + d2[d];
    }
    float dot = xl[0] * dv[0] + xl[1] * dv[1] + xl[2] * dv[2];
    float dsq = dv[0] * dv[0] + dv[1] * dv[1] + dv[2] * dv[2];
    acc0 = fmaf(av, lrelu_combine(xl[0], dv[0], dot, dsq), acc0);
    acc1 = fmaf(av, lrelu_combine(xl[1], dv[1], dot, dsq), acc1);
    acc2 = fmaf(av, lrelu_combine(xl[2], dv[2], dot, dsq), acc2);
  }
  out[r0 + n] = xres[r0 + n] + acc0;
  out[r0 + N + n] = xres[r0 + N + n] + acc1;
  out[r0 + 2 * (size_t)N + n] = xres[r0 + 2 * (size_t)N + n] + acc2;
}

// ---------------- g-fuse finisher: elementwise lrelu ----------------
__global__ void __launch_bounds__(256) k_gfin(const float* __restrict__ XL, const float* __restrict__ DV,
                                              float* __restrict__ out, int N) {
  int gi = blockIdx.x * 256 + threadIdx.x;
  int total = 2 * 64 * N;
  if (gi >= total) return;
  int n = gi % N;
  int t = gi / N;
  int o = t & 63, b = t >> 6;
  size_t r0 = (size_t)((b * 64 + o) * 3) * N;
  float xl[3], dv[3];
#pragma unroll
  for (int d = 0; d < 3; ++d) { xl[d] = XL[r0 + (size_t)d * N + n]; dv[d] = DV[r0 + (size_t)d * N + n]; }
  float dot = xl[0] * dv[0] + xl[1] * dv[1] + xl[2] * dv[2];
  float dsq = dv[0] * dv[0] + dv[1] * dv[1] + dv[2] * dv[2];
#pragma unroll
  for (int d = 0; d < 3; ++d) out[r0 + (size_t)d * N + n] = lrelu_combine(xl[d], dv[d], dot, dsq);
}

// ---------------- bias for g-fuse: cb[b][o][d] = sum_c G2[o][c]*mean[b][c*3+d] ----------------
__global__ void k_gbias(const float* __restrict__ gw, const float* __restrict__ meanb,
                        float* __restrict__ cb) {
  int b = blockIdx.x, tid = threadIdx.x;  // 192 threads
  int o = tid / 3, d = tid - o * 3;
  const float* mb = meanb + b * 192;
  float s = 0.f;
  for (int c = 0; c < 64; ++c) s = fmaf(gw[o * 128 + 64 + c], mb[c * 3 + d], s);
  cb[b * 192 + tid] = s;
}

// ---------------- column mean over N for all 192 (c,dd) ----------------
__global__ void k_cmean(const float* __restrict__ x, float* __restrict__ out,
                        int N, int ostride, int obase, float inv) {
  __shared__ float red[256];
  int b = blockIdx.y, cd = blockIdx.x, tid = threadIdx.x;
  const float* p = x + ((size_t)b * 192 + cd) * N;
  float s = 0.f;
  for (int i = tid; i < N; i += 256) s += p[i];
  red[tid] = s;
  __syncthreads();
  for (int st = 128; st > 0; st >>= 1) {
    if (tid < st) red[tid] += red[tid + st];
    __syncthreads();
  }
  if (tid == 0) out[(size_t)b * ostride + obase + cd] = red[0] * inv;
}

// ---------------- channel-mean (fx_par pre-normalization) for both arrays ----------------
__global__ void k_parmean(const float* __restrict__ fx, const float* __restrict__ fy,
                          float* __restrict__ px, float* __restrict__ py, int N, int B) {
  int gi = blockIdx.x * 256 + threadIdx.x;
  int total = B * 3 * N;
  if (gi >= total) return;
  int b = gi / (3 * N);
  int r = gi - b * 3 * N;
  const float* fxb = fx + (size_t)b * 192 * N + r;
  const float* fyb = fy + (size_t)b * 192 * N + r;
  float sx = 0.f, sy = 0.f;
  for (int c = 0; c < 64; ++c) { sx += fxb[(size_t)c * 3 * N]; sy += fyb[(size_t)c * 3 * N]; }
  px[gi] = sx * (1.f / 64.f);
  py[gi] = sy * (1.f / 64.f);
}

// ---------------- score logits: sum_c (fx.px)(fy.py) (softmax+norm skipped: monotone) ----------------
__global__ void k_dotphi(const float* __restrict__ fx, const float* __restrict__ fy,
                         const float* __restrict__ px, const float* __restrict__ py,
                         float* __restrict__ dps, int N, int B) {
  int gi = blockIdx.x * 256 + threadIdx.x;
  if (gi >= B * N) return;
  int b = gi / N, n = gi - b * N;
  const float* fxb = fx + (size_t)b * 192 * N + n;
  const float* fyb = fy + (size_t)b * 192 * N + n;
  const float* pxb = px + (size_t)b * 3 * N + n;
  const float* pyb = py + (size_t)b * 3 * N + n;
  float acc = 0.f;
  for (int c = 0; c < 64; ++c) {
    float ax = 0.f, ay = 0.f;
    for (int d = 0; d < 3; ++d) {
      ax = fmaf(fxb[(size_t)(c * 3 + d) * N], pxb[(size_t)d * N], ax);
      ay = fmaf(fyb[(size_t)(c * 3 + d) * N], pyb[(size_t)d * N], ay);
    }
    acc = fmaf(ax, ay, acc);
  }
  dps[gi] = acc;
}

// ---------------- top-N/2 selection: bitonic sort (desc value, asc index) ----------------
__global__ void __launch_bounds__(1024) k_topsel(const float* __restrict__ dps,
                                                 int* __restrict__ sel, int N, int Nh) {
  __shared__ float kv[2048];
  __shared__ int ki[2048];
  int b = blockIdx.x, tid = threadIdx.x;
  for (int i = tid; i < N; i += 1024) { kv[i] = dps[b * N + i]; ki[i] = i; }
  __syncthreads();
  for (int kk = 2; kk <= N; kk <<= 1) {
    for (int jj = kk >> 1; jj > 0; jj >>= 1) {
      for (int i = tid; i < N; i += 1024) {
        int ixj = i ^ jj;
        if (ixj > i) {
          float va = kv[i], vb = kv[ixj];
          int ia = ki[i], ib = ki[ixj];
          bool aFirst = (va > vb) || (va == vb && ia < ib);
          bool up = ((i & kk) == 0);
          bool doswap = up ? (!aFirst) : aFirst;
          if (doswap) { kv[i] = vb; kv[ixj] = va; ki[i] = ib; ki[ixj] = ia; }
        }
      }
      __syncthreads();
    }
  }
  for (int i = tid; i < Nh; i += 1024) sel[b * Nh + i] = ki[i];
}

// ---------------- gather selected points for both arrays ----------------
__global__ void k_gather(const float* __restrict__ sx, const float* __restrict__ sy,
                         const int* __restrict__ sel,
                         float* __restrict__ dx, float* __restrict__ dy,
                         int N, int Nh, int B) {
  int gi = blockIdx.x * 256 + threadIdx.x;
  int total = B * 192 * Nh;
  if (gi >= total) return;
  int i = gi % Nh;
  int t = gi / Nh;
  int cd = t % 192;
  int b = t / 192;
  int s = sel[b * Nh + i];
  dx[gi] = sx[((size_t)b * 192 + cd) * N + s];
  dy[gi] = sy[((size_t)b * 192 + cd) * N + s];
}

// ---------------- final head: vn_lin_lrelu(concat blocks, h_w, h_d) ----------------
__global__ void k_head(const float* __restrict__ blkX, const float* __restrict__ blkY,
                       const float* __restrict__ hw, const float* __restrict__ hd,
                       float* __restrict__ Fx, float* __restrict__ Fy) {
  __shared__ float f[3][128];
  __shared__ float xl[3][32];
  __shared__ float dv[3][32];
  int which = blockIdx.x, b = blockIdx.y, tid = threadIdx.x;
  const float* blk = which ? blkY : blkX;
  float* F = which ? Fy : Fx;
  int o = tid & 31, dd = tid >> 5;
  for (int i = tid; i < 384; i += 96) f[i % 3][i / 3] = blk[(size_t)b * 384 + i];
  __syncthreads();
  float s = 0.f;
  for (int c = 0; c < 128; ++c) s = fmaf(hw[o * 128 + c], f[dd][c], s);
  xl[dd][o] = s;
  __syncthreads();
  float s2 = 0.f;
  for (int p = 0; p < 32; ++p) s2 = fmaf(hd[o * 32 + p], xl[dd][p], s2);
  dv[dd][o] = s2;
  __syncthreads();
  float dot = xl[0][o] * dv[0][o] + xl[1][o] * dv[1][o] + xl[2][o] * dv[2][o];
  float dsq = dv[0][o] * dv[0][o] + dv[1][o] * dv[1][o] + dv[2][o] * dv[2][o];
  F[((size_t)b * 32 + o) * 3 + dd] = lrelu_combine(xl[dd][o], dv[dd][o], dot, dsq);
}

// ================== LAPACK-faithful 3x3 SVD (dgesdd path: dgebrd + dbdsqr) ==================
#define DEPS 2.220446049250313e-16
#define DUNFL 2.2250738585072014e-308

static __device__ void dlartg_(double f, double g, double* cs, double* sn, double* r) {
  if (g == 0.0) { *cs = 1.0; *sn = 0.0; *r = f; }
  else if (f == 0.0) { *cs = 0.0; *sn = copysign(1.0, g); *r = fabs(g); }
  else {
    double d = sqrt(f * f + g * g);
    double c = fabs(f) / d;
    double rr = copysign(d, f);
    *cs = c; *r = rr; *sn = g / rr;
  }
}

static __device__ void dlas2_(double f, double g, double h, double* ssmin, double* ssmax) {
  double fa = fabs(f), ga = fabs(g), ha = fabs(h);
  double fhmn = fmin(fa, ha), fhmx = fmax(fa, ha);
  if (fhmn == 0.0) {
    *ssmin = 0.0;
    if (fhmx == 0.0) *ssmax = ga;
    else { double mx = fmax(fhmx, ga), mn = fmin(fhmx, ga); double q = mn / mx; *ssmax = mx * sqrt(1.0 + q * q); }
  } else {
    if (ga < fhmx) {
      double as_ = 1.0 + fhmn / fhmx;
      double at = (fhmx - fhmn) / fhmx;
      double au = ga / fhmx; au = au * au;
      double c = 2.0 / (sqrt(as_ * as_ + au) + sqrt(at * at + au));
      *ssmin = fhmn * c; *ssmax = fhmx / c;
    } else {
      double au = fhmx / ga;
      if (au == 0.0) { *ssmin = (fhmn * fhmx) / ga; *ssmax = ga; }
      else {
        double as_ = 1.0 + fhmn / fhmx;
        double at = (fhmx - fhmn) / fhmx;
        double t1 = as_ * au, t2 = at * au;
        double c = 1.0 / (sqrt(1.0 + t1 * t1) + sqrt(1.0 + t2 * t2));
        double sm = (fhmn * c) * au; *ssmin = sm + sm;
        *ssmax = ga / (c + c);
      }
    }
  }
}

static __device__ void dlasv2_(double f, double g, double h,
                               double* ssmin, double* ssmax,
                               double* snr, double* csr, double* snl, double* csl) {
  double ft = f, fa = fabs(f), ht = h, ha = fabs(h);
  int pmax = 1;
  bool swp = (ha > fa);
  if (swp) { pmax = 3; double t = ft; ft = ht; ht = t; t = fa; fa = ha; ha = t; }
  double gt = g, ga = fabs(g);
  double clt = 0, crt = 0, slt = 0, srt = 0;
  if (ga == 0.0) {
    *ssmin = ha; *ssmax = fa; clt = 1.0; crt = 1.0; slt = 0.0; srt = 0.0;
  } else {
    bool gasmal = true;
    if (ga > fa) {
      pmax = 2;
      if ((fa / ga) < DEPS) {
        gasmal = false;
        *ssmax = ga;
        *ssmin = (ha > 1.0) ? (fa / (ga / ha)) : ((fa / ga) * ha);
        clt = 1.0; slt = ht / gt; srt = 1.0; crt = ft / gt;
      }
    }
    if (gasmal) {
      double dd = fa - ha;
      double l = (dd == fa) ? 1.0 : (dd / fa);
      double mq = gt / ft;
      double t = 2.0 - l;
      double mm = mq * mq, tt = t * t;
      double s = sqrt(tt + mm);
      double r = (l == 0.0) ? fabs(mq) : sqrt(l * l + mm);
      double a = 0.5 * (s + r);
      *ssmin = ha / a;
      *ssmax = fa * a;
      if (mm == 0.0) {
        if (l == 0.0) t = copysign(2.0, ft) * copysign(1.0, gt);
        else t = gt / copysign(dd, ft) + mq / t;
      } else {
        t = (mq / (s + t) + mq / (r + l)) * (1.0 + a);
      }
      double l2 = sqrt(t * t + 4.0);
      crt = 2.0 / l2;
      srt = t / l2;
      clt = (crt + srt * mq) / a;
      slt = (ht / ft) * srt / a;
    }
  }
  if (swp) { *csl = srt; *snl = crt; *csr = slt; *snr = clt; }
  else { *csl = clt; *snl = slt; *csr = crt; *snr = srt; }
  double tsign = 0.0;
  if (pmax == 1) tsign = copysign(1.0, *csr) * copysign(1.0, *csl) * copysign(1.0, f);
  if (pmax == 2) tsign = copysign(1.0, *snr) * copysign(1.0, *csl) * copysign(1.0, g);
  if (pmax == 3) tsign = copysign(1.0, *snr) * copysign(1.0, *snl) * copysign(1.0, h);
  *ssmax = copysign(*ssmax, tsign);
  *ssmin = copysign(*ssmin, tsign * copysign(1.0, f) * copysign(1.0, h));
}

static __device__ void dbdsqr3(double d[3], double e[2], double VT[3][3], double U[3][3]) {
  const int n = 3;
  double tolmul = fmax(10.0, fmin(100.0, pow(DEPS, -0.125)));
  double tol = tolmul * DEPS;
  double thresh;
  {
    double sminoa = fabs(d[0]);
    if (sminoa != 0.0) {
      double mu = sminoa;
      for (int i = 1; i < n; ++i) {
        mu = fabs(d[i]) * (mu / (mu + fabs(e[i - 1])));
        sminoa = fmin(sminoa, mu);
        if (sminoa == 0.0) break;
      }
    }
    sminoa = sminoa / sqrt((double)n);
    thresh = fmax(tol * sminoa, 6.0 * n * n * DUNFL);
  }
  int maxit = 6 * n * n;
  int iter = 0, oldll = -1, oldm = -1, idir = 0;
  int m = n;
  double sminl = 0.0;
  int guard = 0;
  while (true) {
    if (m <= 1) break;
    if (iter > maxit) break;
    if (++guard > 500) break;
    double smaxb = fabs(d[m - 1]);
    int ll = 0; bool found = false;
    for (int lll = 1; lll <= m - 1; ++lll) {
      int l = m - lll;
      double abss = fabs(d[l - 1]);
      double abse = fabs(e[l - 1]);
      if (abse <= thresh) { ll = l; found = true; break; }
      smaxb = fmax(smaxb, fmax(abss, abse));
    }
    if (found) {
      e[ll - 1] = 0.0;
      if (ll == m - 1) { m = m - 1; continue; }
      ll = ll + 1;
    } else ll = 1;
    if (ll == m - 1) {
      double sigmn, sigmx, sinr, cosr, sinl2, cosl2;
      dlasv2_(d[m - 2], e[m - 2], d[m - 1], &sigmn, &sigmx, &sinr, &cosr, &sinl2, &cosl2);
      d[m - 2] = sigmx; d[m - 1] = sigmn; e[m - 2] = 0.0;
      for (int j = 0; j < 3; ++j) {
        double t1 = VT[m - 2][j], t2 = VT[m - 1][j];
        VT[m - 2][j] = cosr * t1 + sinr * t2;
        VT[m - 1][j] = cosr * t2 - sinr * t1;
      }
      for (int i2 = 0; i2 < 3; ++i2) {
        double t1 = U[i2][m - 2], t2 = U[i2][m - 1];
        U[i2][m - 2] = cosl2 * t1 + sinl2 * t2;
        U[i2][m - 1] = cosl2 * t2 - sinl2 * t1;
      }
      m -= 2;
      continue;
    }
    if (ll > oldm || m < oldll)
      idir = (fabs(d[ll - 1]) >= fabs(d[m - 1])) ? 1 : 2;
    if (idir == 1) {
      if (fabs(e[m - 2]) <= tol * fabs(d[m - 1])) { e[m - 2] = 0.0; continue; }
      double mu = fabs(d[ll - 1]); sminl = mu;
      bool conv = true;
      for (int lll = ll; lll <= m - 1; ++lll) {
        if (fabs(e[lll - 1]) > tol * mu) { conv = false; break; }
        mu = fabs(d[lll]) * (mu / (mu + fabs(e[lll - 1])));
        sminl = fmin(sminl, mu);
      }
      if (conv) { e[m - 2] = 0.0; continue; }
    } else {
      if (fabs(e[ll - 1]) <= tol * fabs(d[ll - 1])) { e[ll - 1] = 0.0; continue; }
      double mu = fabs(d[m - 1]); sminl = mu;
      bool conv = true;
      for (int lll = m - 1; lll >= ll; --lll) {
        if (fabs(e[lll - 1]) > tol * mu) { conv = false; break; }
        mu = fabs(d[lll - 1]) * (mu / (mu + fabs(e[lll - 1])));
        sminl = fmin(sminl, mu);
      }
      if (conv) { e[ll - 1] = 0.0; continue; }
    }
    oldll = ll; oldm = m;
    double shift = 0.0, rr;
    if (!(n * tol * (sminl / smaxb) <= fmax(DEPS, 0.01 * tol))) {
      double sll;
      if (idir == 1) { sll = fabs(d[ll - 1]); dlas2_(d[m - 2], e[m - 2], d[m - 1], &shift, &rr); }
      else { sll = fabs(d[m - 1]); dlas2_(d[ll - 1], e[ll - 1], d[ll], &shift, &rr); }
      if (sll > 0.0) { double q = shift / sll; if (q * q < DEPS) shift = 0.0; }
    }
    iter += m - ll;
    double csv[2], snv[2], ocsv[2], osnv[2];
    int cnt = 0;
    if (shift == 0.0) {
      if (idir == 1) {
        double cs = 1.0, oldcs = 1.0, sn = 0.0, oldsn = 0.0, r;
        for (int i = ll; i <= m - 1; ++i) {
          dlartg_(d[i - 1] * cs, e[i - 1], &cs, &sn, &r);
          if (i > ll) e[i - 2] = oldsn * r;
          dlartg_(oldcs * r, d[i] * sn, &oldcs, &oldsn, &d[i - 1]);
          csv[cnt] = cs; snv[cnt] = sn; ocsv[cnt] = oldcs; osnv[cnt] = oldsn; cnt++;
        }
        double hh = d[m - 1] * cs;
        d[m - 1] = hh * oldcs;
        e[m - 2] = hh * oldsn;
        for (int k = 0; k < cnt; ++k) {
          int r0 = ll - 1 + k, r1 = r0 + 1;
          for (int j = 0; j < 3; ++j) {
            double t1 = VT[r0][j], t2 = VT[r1][j];
            VT[r0][j] = snv[k] * t2 + csv[k] * t1;
            VT[r1][j] = csv[k] * t2 - snv[k] * t1;
          }
        }
        for (int k = 0; k < cnt; ++k) {
          int c0 = ll - 1 + k, c1 = c0 + 1;
          for (int i2 = 0; i2 < 3; ++i2) {
            double t1 = U[i2][c0], t2 = U[i2][c1];
            U[i2][c0] = osnv[k] * t2 + ocsv[k] * t1;
            U[i2][c1] = ocsv[k] * t2 - osnv[k] * t1;
          }
        }
        if (fabs(e[m - 2]) <= thresh) e[m - 2] = 0.0;
      } else {
        double cs = 1.0, oldcs = 1.0, sn = 0.0, oldsn = 0.0, r;
        for (int i = m; i >= ll + 1; --i) {
          dlartg_(d[i - 1] * cs, e[i - 2], &cs, &sn, &r);
          if (i < m) e[i - 1] = oldsn * r;
          dlartg_(oldcs * r, d[i - 2] * sn, &oldcs, &oldsn, &d[i - 1]);
          int k = i - ll - 1;
          csv[k] = cs; snv[k] = -sn; ocsv[k] = oldcs; osnv[k] = -oldsn; cnt++;
        }
        double hh = d[ll - 1] * cs;
        d[ll - 1] = hh * oldcs;
        e[ll - 1] = hh * oldsn;
        for (int k = cnt - 1; k >= 0; --k) {
          int r0 = ll - 1 + k, r1 = r0 + 1;
          for (int j = 0; j < 3; ++j) {
            double t1 = VT[r0][j], t2 = VT[r1][j];
            VT[r0][j] = osnv[k] * t2 + ocsv[k] * t1;
            VT[r1][j] = ocsv[k] * t2 - osnv[k] * t1;
          }
        }
        for (int k = cnt - 1; k >= 0; --k) {
          int c0 = ll - 1 + k, c1 = c0 + 1;
          for (int i2 = 0; i2 < 3; ++i2) {
            double t1 = U[i2][c0], t2 = U[i2][c1];
            U[i2][c0] = snv[k] * t2 + csv[k] * t1;
            U[i2][c1] = csv[k] * t2 - snv[k] * t1;
          }
        }
        if (fabs(e[ll - 1]) <= thresh) e[ll - 1] = 0.0;
      }
    } else {
      if (idir == 1) {
        double f = (fabs(d[ll - 1]) - shift) * (copysign(1.0, d[ll - 1]) + shift / d[ll - 1]);
        double g = e[ll - 1];
        double cosr, sinr, cosl2, sinl2, r;
        for (int i = ll; i <= m - 1; ++i) {
          dlartg_(f, g, &cosr, &sinr, &r);
          if (i > ll) e[i - 2] = r;
          f = cosr * d[i - 1] + sinr * e[i - 1];
          e[i - 1] = cosr * e[i - 1] - sinr * d[i - 1];
          g = sinr * d[i];
          d[i] = cosr * d[i];
          dlartg_(f, g, &cosl2, &sinl2, &r);
          d[i - 1] = r;
          f = cosl2 * e[i - 1] + sinl2 * d[i];
          d[i] = cosl2 * d[i] - sinl2 * e[i - 1];
          if (i < m - 1) {
            g = sinl2 * e[i];
            e[i] = cosl2 * e[i];
          }
          csv[cnt] = cosr; snv[cnt] = sinr; ocsv[cnt] = cosl2; osnv[cnt] = sinl2; cnt++;
        }
        e[m - 2] = f;
        for (int k = 0; k < cnt; ++k) {
          int r0 = ll - 1 + k, r1 = r0 + 1;
          for (int j = 0; j < 3; ++j) {
            double t1 = VT[r0][j], t2 = VT[r1][j];
            VT[r0][j] = snv[k] * t2 + csv[k] * t1;
            VT[r1][j] = csv[k] * t2 - snv[k] * t1;
          }
        }
        for (int k = 0; k < cnt; ++k) {
          int c0 = ll - 1 + k, c1 = c0 + 1;
          for (int i2 = 0; i2 < 3; ++i2) {
            double t1 = U[i2][c0], t2 = U[i2][c1];
            U[i2][c0] = osnv[k] * t2 + ocsv[k] * t1;
            U[i2][c1] = ocsv[k] * t2 - osnv[k] * t1;
          }
        }
        if (fabs(e[m - 2]) <= thresh) e[m - 2] = 0.0;
      } else {
        double f = (fabs(d[m - 1]) - shift) * (copysign(1.0, d[m - 1]) + shift / d[m - 1]);
        double g = e[m - 2];
        for (int i = m; i >= ll + 1; --i) {
          double cosr, sinr, cosl2, sinl2, r;
          dlartg_(f, g, &cosr, &sinr, &r);
          if (i < m) e[i - 1] = r;
          f = cosr * d[i - 1] + sinr * e[i - 2];
          e[i - 2] = cosr * e[i - 2] - sinr * d[i - 1];
          g = sinr * d[i - 2];
          d[i - 2] = cosr * d[i - 2];
          dlartg_(f, g, &cosl2, &sinl2, &r);
          d[i - 1] = r;
          f = cosl2 * e[i - 2] + sinl2 * d[i - 2];
          d[i - 2] = cosl2 * d[i - 2] - sinl2 * e[i - 2];
          if (i > ll + 1) {
            g = sinl2 * e[i - 3];
            e[i - 3] = cosl2 * e[i - 3];
          }
          int k = i - ll - 1;
          ocsv[k] = cosl2; osnv[k] = -sinl2; csv[k] = cosr; snv[k] = -sinr; cnt++;
        }
        e[ll - 1] = f;
        for (int k = cnt - 1; k >= 0; --k) {
          int r0 = ll - 1 + k, r1 = r0 + 1;
          for (int j = 0; j < 3; ++j) {
            double t1 = VT[r0][j], t2 = VT[r1][j];
            VT[r0][j] = snv[k] * t2 + csv[k] * t1;
            VT[r1][j] = csv[k] * t2 - snv[k] * t1;
          }
        }
        for (int k = cnt - 1; k >= 0; --k) {
          int c0 = ll - 1 + k, c1 = c0 + 1;
          for (int i2 = 0; i2 < 3; ++i2) {
            double t1 = U[i2][c0], t2 = U[i2][c1];
            U[i2][c0] = osnv[k] * t2 + ocsv[k] * t1;
            U[i2][c1] = ocsv[k] * t2 - osnv[k] * t1;
          }
        }
        if (fabs(e[ll - 1]) <= thresh) e[ll - 1] = 0.0;
      }
    }
  }
  for (int i = 0; i < n; ++i)
    if (d[i] < 0.0) { d[i] = -d[i]; for (int j = 0; j < 3; ++j) VT[i][j] = -VT[i][j]; }
  for (int i = 1; i <= n - 1; ++i) {
    int isub = 1; double smn = d[0];
    for (int j = 2; j <= n + 1 - i; ++j)
      if (d[j - 1] <= smn) { isub = j; smn = d[j - 1]; }
    if (isub != n + 1 - i) {
      int a = isub - 1, b2 = n - i;
      double t = d[a]; d[a] = d[b2]; d[b2] = t;
      for (int j = 0; j < 3; ++j) { t = VT[a][j]; VT[a][j] = VT[b2][j]; VT[b2][j] = t; }
      for (int j = 0; j < 3; ++j) { t = U[j][a]; U[j][a] = U[j][b2]; U[j][b2] = t; }
    }
  }
}

__global__ void k_svd(const float* __restrict__ Fx, const float* __restrict__ Fy,
                      float* __restrict__ out, int B) {
  int b = blockIdx.x;
  if (threadIdx.x != 0) return;
  double A[3][3];
  for (int d = 0; d < 3; ++d)
    for (int e = 0; e < 3; ++e) {
      double s = 0.0;
      for (int c = 0; c < 32; ++c)
        s += (double)Fx[((size_t)b * 32 + c) * 3 + d] * (double)Fy[((size_t)b * 32 + c) * 3 + e];
      A[d][e] = s;
    }
  double dg[3], eg[2], tauq0, tauq1, taup0;
  double v1_1 = 0, v1_2 = 0, v2_1 = 0, w1 = 0;
  {
    double alpha = A[0][0];
    double xn = sqrt(A[1][0] * A[1][0] + A[2][0] * A[2][0]);
    if (xn == 0.0) { tauq0 = 0.0; dg[0] = alpha; }
    else {
      double beta = -copysign(sqrt(alpha * alpha + xn * xn), alpha);
      tauq0 = (beta - alpha) / beta;
      double scal = 1.0 / (alpha - beta);
      v1_1 = A[1][0] * scal; v1_2 = A[2][0] * scal;
      dg[0] = beta;
    }
    for (int j = 1; j < 3; ++j) {
      double w = A[0][j] + v1_1 * A[1][j] + v1_2 * A[2][j];
      w *= tauq0;
      A[0][j] -= w; A[1][j] -= w * v1_1; A[2][j] -= w * v1_2;
    }
  }
  {
    double alpha = A[0][1];
    double xn = fabs(A[0][2]);
    if (xn == 0.0) { taup0 = 0.0; eg[0] = alpha; }
    else {
      double beta = -copysign(sqrt(alpha * alpha + xn * xn), alpha);
      taup0 = (beta - alpha) / beta;
      w1 = A[0][2] / (alpha - beta);
      eg[0] = beta;
    }
    for (int i = 1; i < 3; ++i) {
      double t = A[i][1] + w1 * A[i][2];
      t *= taup0;
      A[i][1] -= t; A[i][2] -= t * w1;
    }
  }
  {
    double alpha = A[1][1];
    double xn = fabs(A[2][1]);
    if (xn == 0.0) { tauq1 = 0.0; dg[1] = alpha; }
    else {
      double beta = -copysign(sqrt(alpha * alpha + xn * xn), alpha);
      tauq1 = (beta - alpha) / beta;
      v2_1 = A[2][1] / (alpha - beta);
      dg[1] = beta;
    }
    double w = A[1][2] + v2_1 * A[2][2];
    w *= tauq1;
    A[1][2] -= w; A[2][2] -= w * v2_1;
  }
  eg[1] = A[1][2];
  dg[2] = A[2][2];
  double U[3][3] = {{1, 0, 0}, {0, 1, 0}, {0, 0, 1}};
  double VT[3][3] = {{1, 0, 0}, {0, 1, 0}, {0, 0, 1}};
  dbdsqr3(dg, eg, VT, U);
  for (int j = 0; j < 3; ++j) {
    double w = U[1][j] + v2_1 * U[2][j];
    w *= tauq1;
    U[1][j] -= w; U[2][j] -= w * v2_1;
  }
  for (int j = 0; j < 3; ++j) {
    double w = U[0][j] + v1_1 * U[1][j] + v1_2 * U[2][j];
    w *= tauq0;
    U[0][j] -= w; U[1][j] -= w * v1_1; U[2][j] -= w * v1_2;
  }
  for (int r = 0; r < 3; ++r) {
    double t = VT[r][1] + w1 * VT[r][2];
    t *= taup0;
    VT[r][1] -= t; VT[r][2] -= t * w1;
  }
  for (int i = 0; i < 3; ++i)
    for (int j = 0; j < 3; ++j) {
      double r = 0;
      for (int k = 0; k < 3; ++k) r += U[i][k] * VT[j][k];
      out[b * 9 + i * 3 + j] = (float)r;
    }
  for (int dd = 0; dd < 3; ++dd) {
    float sx = 0.f, sy = 0.f;
    for (int c = 0; c < 32; ++c) {
      float vx = Fx[((size_t)b * 32 + c) * 3 + dd];
      float vy = Fy[((size_t)b * 32 + c) * 3 + dd];
      sx = fmaf(vx, vx, sx);
      sy = fmaf(vy, vy, sy);
    }
    out[B * 9 + b * 3 + dd] = sqrtf(sy) / sqrtf(sx);
  }
}

extern "C" void kernel_launch(void* const* d_in, const int* in_sizes, int n_in,
                              void* d_out, int out_size, void* d_ws, size_t ws_size,
                              hipStream_t stream) {
  (void)in_sizes; (void)n_in; (void)out_size; (void)ws_size;
  const int B = 2, N0 = 2048;
  const float* W[24];
  for (int i = 0; i < 24; ++i) W[i] = (const float*)d_in[i];

  float* ws = (float*)d_ws;
  const size_t P = (size_t)B * 64 * 3 * 2048;  // 786432
  float* bufA = ws;
  float* bufB = bufA + P;
  float* bufC = bufB + P;
  float* bufD = bufC + P;
  float* bufQ = bufD + P;
  float* G1 = bufQ + P;
  float* G2 = G1 + P;
  float* G3 = G2 + P;
  float* G4 = G3 + P;
  float* logits = G4 + P;            // B*2*2048*16 = 131072
  float* att = logits + 131072;      // 131072
  float* px = att + 131072;          // B*3*2048 = 12288
  float* py = px + 12288;
  float* dps = py + 12288;           // 4096
  float* xxb = dps + 4096;           // 4096
  float* meanX = xxb + 4096;         // 384
  float* meanY = meanX + 384;
  float* cbX = meanY + 384;          // 384
  float* cbY = cbX + 384;
  float* blkX = cbY + 384;           // 768
  float* blkY = blkX + 768;
  float* Fxb = blkY + 768;           // 192
  float* Fyb = Fxb + 192;
  int* idxA = (int*)(Fyb + 192);     // 65536
  int* idxB = idxA + 65536;
  int* sel = idxB + 65536;           // 2048

  auto xxknn = [&](const float* x, int D, int N, int* idx) {
    dim3 g1((N + 255) / 256, B);
    k_xx<<<g1, 256, 0, stream>>>(x, xxb, D, N);
    dim3 g2(N, B);
    k_knn<<<g2, 256, 0, stream>>>(x, xxb, idx, D, N);
  };
  auto lin64 = [&](const float* Wm, int wsd, int woff, int sub, const float* X,
                   const float* bias, float* out, int N) {
    dim3 g((3 * N + 255) / 256, B, 4);
    k_lin<64><<<g, 256, 0, stream>>>(Wm, wsd, woff, sub, X, bias, out, N);
  };
  auto lin1 = [&](const float* Wm, int wsd, int woff, int sub, const float* X,
                  float* out, int N) {
    dim3 g((3 * N + 255) / 256, B, 4);
    k_lin<1><<<g, 256, 0, stream>>>(Wm, wsd, woff, sub, X, nullptr, out, N);
  };

  const float* fx = W[0];
  const float* fy = W[1];
  int N = N0;
  for (int blk = 0; blk < 2; ++blk) {
    int C = (blk == 0) ? 1 : 64;
    int D = C * 3;
    const float* dgw = W[blk ? 12 : 2]; const float* dgd = W[blk ? 13 : 3];
    const float* qw  = W[blk ? 14 : 4]; const float* qd  = W[blk ? 15 : 5];
    const float* kw  = W[blk ? 16 : 6]; const float* kd  = W[blk ? 17 : 7];
    const float* vw  = W[blk ? 18 : 8]; const float* vd  = W[blk ? 19 : 9];
    const float* gw  = W[blk ? 20 : 10]; const float* gd = W[blk ? 21 : 11];
    int nEl = B * 64 * N;
    dim3 gE((nEl + 255) / 256);
    dim3 gW(B * N / 4);              // wave-per-point kernels
    dim3 gK(B * N * 16 / 4);         // wave-per-edge kernels
    dim3 gS((B * 2 * N + 255) / 256);

    // ---- dgcnn fx -> bufA
    xxknn(fx, D, N, idxA);
    if (blk == 0) { lin1(dgw, 2, 0, 0, fx, G1, N); lin1(dgw, 2, 1, 1, fx, G2, N); }
    else { lin64(dgw, 128, 0, 0, fx, nullptr, G1, N); lin64(dgw, 128, 64, 1, fx, nullptr, G2, N); }
    lin64(dgd, 64, 0, 0, G1, nullptr, G3, N);
    lin64(dgd, 64, 0, 0, G2, nullptr, G4, N);
    k_edge2<<<gE, 256, 0, stream>>>(G1, G2, G3, G4, idxA, bufA, N);
    // ---- dgcnn fy -> bufB
    xxknn(fy, D, N, idxB);
    if (blk == 0) { lin1(dgw, 2, 0, 0, fy, G1, N); lin1(dgw, 2, 1, 1, fy, G2, N); }
    else { lin64(dgw, 128, 0, 0, fy, nullptr, G1, N); lin64(dgw, 128, 64, 1, fy, nullptr, G2, N); }
    lin64(dgd, 64, 0, 0, G1, nullptr, G3, N);
    lin64(dgd, 64, 0, 0, G2, nullptr, G4, N);
    k_edge2<<<gE, 256, 0, stream>>>(G1, G2, G3, G4, idxB, bufB, N);

    // ---- cross_context #1: x=bufA, y=bufB -> bufC
    xxknn(bufB, 192, N, idxB);
    lin64(qw, 64, 0, 0, bufA, nullptr, G1, N);
    lin64(qd, 64, 0, 0, G1, nullptr, G2, N);
    k_qfin<<<gW, 256, 0, stream>>>(G1, G2, bufQ, N);
    lin64(kw, 128, 0, 0, bufB, nullptr, G1, N);
    lin64(kw, 128, 64, 1, bufB, nullptr, G2, N);
    lin64(kd, 64, 0, 0, G1, nullptr, G3, N);
    lin64(kd, 64, 0, 0, G2, nullptr, G4, N);
    k_klog2<<<gK, 256, 0, stream>>>(bufQ, G1, G2, G3, G4, idxB, logits, N);
    k_soft<<<gS, 256, 0, stream>>>(logits, att, N);
    lin64(vw, 128, 0, 0, bufB, nullptr, G1, N);
    lin64(vw, 128, 64, 1, bufB, nullptr, G2, N);
    lin64(vd, 64, 0, 0, G1, nullptr, G3, N);
    lin64(vd, 64, 0, 0, G2, nullptr, G4, N);
    k_attout2<<<gE, 256, 0, stream>>>(bufA, G1, G2, G3, G4, att, idxB, bufC, N);

    // ---- cross_context #2: x=bufB, y=bufC -> bufD
    xxknn(bufC, 192, N, idxA);
    lin64(qw, 64, 0, 0, bufB, nullptr, G1, N);
    lin64(qd, 64, 0, 0, G1, nullptr, G2, N);
    k_qfin<<<gW, 256, 0, stream>>>(G1, G2, bufQ, N);
    lin64(kw, 128, 0, 0, bufC, nullptr, G1, N);
    lin64(kw, 128, 64, 1, bufC, nullptr, G2, N);
    lin64(kd, 64, 0, 0, G1, nullptr, G3, N);
    lin64(kd, 64, 0, 0, G2, nullptr, G4, N);
    k_klog2<<<gK, 256, 0, stream>>>(bufQ, G1, G2, G3, G4, idxA, logits, N);
    k_soft<<<gS, 256, 0, stream>>>(logits, att, N);
    lin64(vw, 128, 0, 0, bufC, nullptr, G1, N);
    lin64(vw, 128, 64, 1, bufC, nullptr, G2, N);
    lin64(vd, 64, 0, 0, G1, nullptr, G3, N);
    lin64(vd, 64, 0, 0, G2, nullptr, G4, N);
    k_attout2<<<gE, 256, 0, stream>>>(bufB, G1, G2, G3, G4, att, idxA, bufD, N);

    // ---- global fuse
    dim3 gm(192, B);
    k_cmean<<<gm, 256, 0, stream>>>(bufC, meanX, N, 192, 0, 1.f / (float)N);
    k_cmean<<<gm, 256, 0, stream>>>(bufD, meanY, N, 192, 0, 1.f / (float)N);
    k_gbias<<<dim3(B), 192, 0, stream>>>(gw, meanX, cbX);
    k_gbias<<<dim3(B), 192, 0, stream>>>(gw, meanY, cbY);
    lin64(gw, 128, 0, 0, bufC, cbX, G1, N);
    lin64(gd, 64, 0, 0, G1, nullptr, G2, N);
    k_gfin<<<gE, 256, 0, stream>>>(G1, G2, bufA, N);
    lin64(gw, 128, 0, 0, bufD, cbY, G1, N);
    lin64(gd, 64, 0, 0, G1, nullptr, G2, N);
    k_gfin<<<gE, 256, 0, stream>>>(G1, G2, bufB, N);

    // ---- score + top-half selection
    int Nh = N / 2;
    k_parmean<<<dim3((B * 3 * N + 255) / 256), 256, 0, stream>>>(bufA, bufB, px, py, N, B);
    k_dotphi<<<dim3((B * N + 255) / 256), 256, 0, stream>>>(bufA, bufB, px, py, dps, N, B);
    k_topsel<<<dim3(B), 1024, 0, stream>>>(dps, sel, N, Nh);
    k_gather<<<dim3((B * 192 * Nh + 255) / 256), 256, 0, stream>>>(bufA, bufB, sel, bufC, bufD, N, Nh, B);
    k_cmean<<<gm, 256, 0, stream>>>(bufC, blkX, Nh, 384, blk * 192, 1.f / (float)Nh);
    k_cmean<<<gm, 256, 0, stream>>>(bufD, blkY, Nh, 384, blk * 192, 1.f / (float)Nh);
    fx = bufC; fy = bufD;
    N = Nh;
  }
  k_head<<<dim3(2, B), 96, 0, stream>>>(blkX, blkY, W[22], W[23], Fxb, Fyb);
  k_svd<<<dim3(B), 64, 0, stream>>>(Fxb, Fyb, (float*)d_out, B);
}